// Round 1
// baseline (11163.415 us; speedup 1.0000x reference)
//
#include <hip/hip_runtime.h>
#include <math.h>

#define T_  256
#define B_  32
#define N_  16
#define F_  128
#define H_  256
#define BN_ (B_ * N_)      // 512
#define SPB 4              // sequences per block
#define NBLK (BN_ / SPB)   // 128
#define NTHR H_            // 256: one thread per h element

__device__ __forceinline__ float sigmoidf_(float x) {
    // safe for large |x|: exp(+inf) -> 1/inf = 0 ; exp(0) path -> 1
    return 1.0f / (1.0f + __expf(-x));
}

__device__ __forceinline__ float tanhf_(float x) {
    // tanh(x) = sign(x) * (1 - 2/(exp(2|x|)+1)); safe at large |x| (exp->inf -> t->1)
    float ax = fabsf(x);
    float e  = __expf(2.0f * ax);
    float t  = 1.0f - 2.0f / (e + 1.0f);
    return copysignf(t, x);
}

__global__ __launch_bounds__(NTHR, 1)
void slotgru_persistent_kernel(const float* __restrict__ x,
                               const int*   __restrict__ dones,
                               const float* __restrict__ h0,
                               const float* __restrict__ W_ih,
                               const float* __restrict__ W_hh,
                               const float* __restrict__ b_ih,
                               const float* __restrict__ b_hh,
                               float*       __restrict__ out)
{
    __shared__ __align__(16) float xs[SPB][F_];  // 2 KB
    __shared__ __align__(16) float hs[SPB][H_];  // 4 KB

    const int j   = threadIdx.x;        // h element 0..255
    const int bn0 = blockIdx.x * SPB;   // first sequence of this block

    // Per-thread gate rows: q*H + j for q = 0(r), 1(z), 2(n)
    const float bi0 = b_ih[0 * H_ + j];
    const float bi1 = b_ih[1 * H_ + j];
    const float bi2 = b_ih[2 * H_ + j];
    const float bh0 = b_hh[0 * H_ + j];
    const float bh1 = b_hh[1 * H_ + j];
    const float bh2 = b_hh[2 * H_ + j];

    const float4* wi0 = (const float4*)(W_ih + (size_t)(0 * H_ + j) * F_);
    const float4* wi1 = (const float4*)(W_ih + (size_t)(1 * H_ + j) * F_);
    const float4* wi2 = (const float4*)(W_ih + (size_t)(2 * H_ + j) * F_);
    const float4* wh0 = (const float4*)(W_hh + (size_t)(0 * H_ + j) * H_);
    const float4* wh1 = (const float4*)(W_hh + (size_t)(1 * H_ + j) * H_);
    const float4* wh2 = (const float4*)(W_hh + (size_t)(2 * H_ + j) * H_);

    float hreg[SPB];
    #pragma unroll
    for (int s = 0; s < SPB; ++s) {
        float h = h0[(size_t)(bn0 + s) * H_ + j];
        hreg[s]  = h;
        hs[s][j] = h;
    }

    for (int t = 0; t < T_; ++t) {
        // --- done flags (uniform across block -> scalar loads) ---
        int d[SPB];
        #pragma unroll
        for (int s = 0; s < SPB; ++s) d[s] = dones[(size_t)t * BN_ + bn0 + s];

        // --- stage x[t, bn0..bn0+3, :] : 512 contiguous floats, coalesced ---
        {
            const float* xsrc = x + (size_t)((size_t)t * BN_ + bn0) * F_;
            ((float*)xs)[j]       = xsrc[j];
            ((float*)xs)[j + 256] = xsrc[j + 256];
        }

        // --- done-mask reset of h (owner thread writes) ---
        #pragma unroll
        for (int s = 0; s < SPB; ++s) {
            if (d[s]) hs[s][j] = 0.0f;
        }
        __syncthreads();

        // --- input projection: ax[q][s] = dot(W_ih[q*H+j,:], x[s,:]) ---
        float ax0[SPB] = {0, 0, 0, 0};
        float ax1[SPB] = {0, 0, 0, 0};
        float ax2[SPB] = {0, 0, 0, 0};
        #pragma unroll 8
        for (int c = 0; c < F_ / 4; ++c) {
            float4 w0 = wi0[c];
            float4 w1 = wi1[c];
            float4 w2 = wi2[c];
            #pragma unroll
            for (int s = 0; s < SPB; ++s) {
                float4 xv = ((const float4*)xs[s])[c];
                ax0[s] = fmaf(w0.x, xv.x, fmaf(w0.y, xv.y, fmaf(w0.z, xv.z, fmaf(w0.w, xv.w, ax0[s]))));
                ax1[s] = fmaf(w1.x, xv.x, fmaf(w1.y, xv.y, fmaf(w1.z, xv.z, fmaf(w1.w, xv.w, ax1[s]))));
                ax2[s] = fmaf(w2.x, xv.x, fmaf(w2.y, xv.y, fmaf(w2.z, xv.z, fmaf(w2.w, xv.w, ax2[s]))));
            }
        }

        // --- recurrent projection: ah[q][s] = dot(W_hh[q*H+j,:], h[s,:]) ---
        // hs rows for done seqs are zeroed, so skipping them yields the exact
        // same result (ah = 0) while saving the loads+FMAs. Branch is
        // block-uniform (scalar) -> no divergence.
        float ah0[SPB] = {0, 0, 0, 0};
        float ah1[SPB] = {0, 0, 0, 0};
        float ah2[SPB] = {0, 0, 0, 0};
        const bool anyact = !(d[0] && d[1] && d[2] && d[3]);
        if (anyact) {
            #pragma unroll 4
            for (int c = 0; c < H_ / 4; ++c) {
                float4 w0 = wh0[c];
                float4 w1 = wh1[c];
                float4 w2 = wh2[c];
                #pragma unroll
                for (int s = 0; s < SPB; ++s) {
                    if (!d[s]) {
                        float4 hv = ((const float4*)hs[s])[c];
                        ah0[s] = fmaf(w0.x, hv.x, fmaf(w0.y, hv.y, fmaf(w0.z, hv.z, fmaf(w0.w, hv.w, ah0[s]))));
                        ah1[s] = fmaf(w1.x, hv.x, fmaf(w1.y, hv.y, fmaf(w1.z, hv.z, fmaf(w1.w, hv.w, ah1[s]))));
                        ah2[s] = fmaf(w2.x, hv.x, fmaf(w2.y, hv.y, fmaf(w2.z, hv.z, fmaf(w2.w, hv.w, ah2[s]))));
                    }
                }
            }
        }

        // --- gates + state update ---
        float hnew[SPB];
        #pragma unroll
        for (int s = 0; s < SPB; ++s) {
            float hp = d[s] ? 0.0f : hreg[s];
            float r = sigmoidf_(ax0[s] + bi0 + ah0[s] + bh0);
            float z = sigmoidf_(ax1[s] + bi1 + ah1[s] + bh1);
            float n = tanhf_(ax2[s] + bi2 + r * (ah2[s] + bh2));
            hnew[s] = (1.0f - z) * n + z * hp;
        }

        __syncthreads();  // all dot-readers of hs are done before we overwrite

        #pragma unroll
        for (int s = 0; s < SPB; ++s) {
            hs[s][j] = hnew[s];
            hreg[s]  = hnew[s];
            out[(size_t)((size_t)t * BN_ + bn0 + s) * H_ + j] = hnew[s];
        }
    }

    // final_h = out_seq[T-1]  (stored after the T*BN*H block)
    #pragma unroll
    for (int s = 0; s < SPB; ++s) {
        out[(size_t)T_ * BN_ * H_ + (size_t)(bn0 + s) * H_ + j] = hreg[s];
    }
}

extern "C" void kernel_launch(void* const* d_in, const int* in_sizes, int n_in,
                              void* d_out, int out_size, void* d_ws, size_t ws_size,
                              hipStream_t stream) {
    const float* x     = (const float*)d_in[0];
    const int*   dones = (const int*)  d_in[1];
    const float* h0    = (const float*)d_in[2];
    const float* W_ih  = (const float*)d_in[3];
    const float* W_hh  = (const float*)d_in[4];
    const float* b_ih  = (const float*)d_in[5];
    const float* b_hh  = (const float*)d_in[6];
    float*       out   = (float*)d_out;

    hipLaunchKernelGGL(slotgru_persistent_kernel, dim3(NBLK), dim3(NTHR), 0, stream,
                       x, dones, h0, W_ih, W_hh, b_ih, b_hh, out);
}

// Round 2
// 1366.101 us; speedup vs baseline: 8.1717x; 8.1717x over previous
//
#include <hip/hip_runtime.h>
#include <math.h>

#define T_   256
#define B_   32
#define N_   16
#define F_   128
#define H_   256
#define BN_  512          // B*N
#define G3_  768          // 3*H

typedef __attribute__((ext_vector_type(8))) short  bf16x8;
typedef __attribute__((ext_vector_type(4))) float  f32x4;
typedef __attribute__((ext_vector_type(4))) unsigned short u16x4;

__device__ __forceinline__ unsigned short f2bf(float f) {   // RNE float->bf16
    union { float f; unsigned u; } v; v.f = f;
    unsigned u = v.u + 0x7FFFu + ((v.u >> 16) & 1u);
    return (unsigned short)(u >> 16);
}
__device__ __forceinline__ float bf2f(unsigned short h) {
    union { unsigned u; float f; } v; v.u = ((unsigned)h) << 16;
    return v.f;
}
__device__ __forceinline__ bf16x8 load_pack8(const float* __restrict__ p) {
    f32x4 a = *(const f32x4*)p;
    f32x4 b = *(const f32x4*)(p + 4);
    bf16x8 r;
    r[0]=(short)f2bf(a[0]); r[1]=(short)f2bf(a[1]); r[2]=(short)f2bf(a[2]); r[3]=(short)f2bf(a[3]);
    r[4]=(short)f2bf(b[0]); r[5]=(short)f2bf(b[1]); r[6]=(short)f2bf(b[2]); r[7]=(short)f2bf(b[3]);
    return r;
}
__device__ __forceinline__ float sigmoidf_(float x) { return 1.0f / (1.0f + __expf(-x)); }
__device__ __forceinline__ float tanhf_(float x)    { return 1.0f - 2.0f / (__expf(2.0f * x) + 1.0f); }

// ---------------------------------------------------------------------------
// Phase 1: xg[tb][g] = bf16( x[tb,:]·W_ih[g,:] + b_ih[g] + (g<2H ? b_hh[g] : 0) )
// MFMA GEMM, M=131072 (tb), N=768 (g), K=128. Block: 64 tb rows × all 768 g.
// ---------------------------------------------------------------------------
__global__ __launch_bounds__(512, 2)
void xg_kernel(const float* __restrict__ x, const float* __restrict__ W_ih,
               const float* __restrict__ b_ih, const float* __restrict__ b_hh,
               unsigned short* __restrict__ xg)
{
    const int tid  = threadIdx.x;
    const int wave = tid >> 6, lane = tid & 63;
    const int lr = lane & 15, lg = lane >> 4;
    const int tb0 = blockIdx.x * 64;
    const int g0  = wave * 96;                 // 6 g-tiles per wave

    // B-fragments: B[k][col=g] = W_ih[g][k]  (k contiguous -> 32B loads)
    bf16x8 wf[6][4];
    #pragma unroll
    for (int gt = 0; gt < 6; ++gt)
        #pragma unroll
        for (int kt = 0; kt < 4; ++kt)
            wf[gt][kt] = load_pack8(W_ih + (size_t)(g0 + gt*16 + lr) * F_ + kt*32 + lg*8);

    float bv[6];
    #pragma unroll
    for (int gt = 0; gt < 6; ++gt) {
        int g = g0 + gt*16 + lr;
        bv[gt] = b_ih[g] + (g < 2*H_ ? b_hh[g] : 0.0f);
    }

    for (int tbt = 0; tbt < 4; ++tbt) {
        const int tbb = tb0 + tbt*16;
        bf16x8 af[4];                          // A[row=tb][k]
        #pragma unroll
        for (int kt = 0; kt < 4; ++kt)
            af[kt] = load_pack8(x + (size_t)(tbb + lr) * F_ + kt*32 + lg*8);

        f32x4 acc[6];
        #pragma unroll
        for (int gt = 0; gt < 6; ++gt) acc[gt] = (f32x4){0.f, 0.f, 0.f, 0.f};

        #pragma unroll
        for (int kt = 0; kt < 4; ++kt)
            #pragma unroll
            for (int gt = 0; gt < 6; ++gt)
                acc[gt] = __builtin_amdgcn_mfma_f32_16x16x32_bf16(af[kt], wf[gt][kt], acc[gt], 0, 0, 0);

        // D: row(tb) = lg*4+q, col(g) = lr
        #pragma unroll
        for (int gt = 0; gt < 6; ++gt)
            #pragma unroll
            for (int q = 0; q < 4; ++q) {
                int tb = tbb + lg*4 + q;
                int g  = g0 + gt*16 + lr;
                xg[(size_t)tb * G3_ + g] = f2bf(acc[gt][q] + bv[gt]);
            }
    }
}

// ---------------------------------------------------------------------------
// Phase 2: persistent recurrent kernel. 32 blocks × 512 threads (8 waves).
// Wave w owns j ∈ [32w, 32w+32): 6 m-tiles {r,r,z,z,n,n} × 8 k-tiles of W_hh
// held register-stationary as bf16 MFMA A-fragments (192 VGPR).
// h ping-pongs via LDS in B-fragment-packed layout.
// ---------------------------------------------------------------------------
__global__ __launch_bounds__(512, 2)
void gru_kernel(const unsigned short* __restrict__ xg,
                const int*   __restrict__ dones,
                const float* __restrict__ h0,
                const float* __restrict__ W_hh,
                const float* __restrict__ b_hh,
                float*       __restrict__ out)
{
    // hT[buf][kt][ksub][col(seq)][8 k-elems]  : 16 KB, conflict-free b128 frag reads
    __shared__ __align__(16) unsigned short hT[2][8][4][16][8];

    const int tid  = threadIdx.x;
    const int wave = tid >> 6, lane = tid & 63;
    const int lr = lane & 15;     // seq col (and A-row within tile)
    const int lg = lane >> 4;     // k-chunk / D row group
    const int bn0 = blockIdx.x * 16;
    const int jb  = wave * 32;

    // --- register-stationary W_hh fragments ---
    // m-tile mt: gate = mt>>1, j-offset = (mt&1)*16 ; A row = gate*H + jb + off + lr
    bf16x8 wf[6][8];
    #pragma unroll
    for (int mt = 0; mt < 6; ++mt) {
        const int row = (mt >> 1) * H_ + jb + (mt & 1) * 16 + lr;
        #pragma unroll
        for (int kt = 0; kt < 8; ++kt)
            wf[mt][kt] = load_pack8(W_hh + (size_t)row * H_ + kt*32 + lg*8);
    }

    float bhn[2][4], hp[2][4];
    #pragma unroll
    for (int m2 = 0; m2 < 2; ++m2)
        #pragma unroll
        for (int q = 0; q < 4; ++q) {
            int j = jb + m2*16 + lg*4 + q;
            bhn[m2][q] = b_hh[2*H_ + j];
            hp[m2][q]  = h0[(size_t)(bn0 + lr) * H_ + j];
        }

    // --- stage h0 into hT[0] (each thread: one bf16x8 chunk) ---
    {
        const int col = tid & 15, kb = (tid >> 4) * 8;
        bf16x8 hv = load_pack8(h0 + (size_t)(bn0 + col) * H_ + kb);
        *(bf16x8*)((unsigned short*)hT + (size_t)tid * 8) = hv;
    }
    __syncthreads();

    const unsigned short* xg_base = xg + (size_t)(bn0 + lr) * G3_ + jb + lg*4;
    float* out_base = out + (size_t)(bn0 + lr) * H_ + jb + lg*4;

    int buf = 0;
    for (int t = 0; t < T_; ++t) {
        const int d = dones[t * BN_ + bn0 + lr];
        const short dmask = (short)(d ? 0 : -1);

        // prefetch xg for this step: [gate][m2] 4 consecutive g (8B loads)
        u16x4 xv[3][2];
        #pragma unroll
        for (int gate = 0; gate < 3; ++gate)
            #pragma unroll
            for (int m2 = 0; m2 < 2; ++m2)
                xv[gate][m2] = *(const u16x4*)(xg_base + (size_t)t * BN_ * G3_ + gate * H_ + m2 * 16);

        f32x4 acc[6];
        #pragma unroll
        for (int mt = 0; mt < 6; ++mt) acc[mt] = (f32x4){0.f, 0.f, 0.f, 0.f};

        #pragma unroll
        for (int kt = 0; kt < 8; ++kt) {
            bf16x8 hv = *(const bf16x8*)&hT[buf][kt][lg][lr][0];
            hv = hv & dmask;                    // done-mask: zero this seq column
            #pragma unroll
            for (int mt = 0; mt < 6; ++mt)
                acc[mt] = __builtin_amdgcn_mfma_f32_16x16x32_bf16(wf[mt][kt], hv, acc[mt], 0, 0, 0);
        }

        // elementwise, fully in-accumulator (lane owns j = jb+m2*16+lg*4+q, s = lr)
        #pragma unroll
        for (int m2 = 0; m2 < 2; ++m2) {
            f32x4 hnew4;
            u16x4 hb;
            #pragma unroll
            for (int q = 0; q < 4; ++q) {
                float xr = bf2f(xv[0][m2][q]);
                float xz = bf2f(xv[1][m2][q]);
                float xn = bf2f(xv[2][m2][q]);
                float r = sigmoidf_(acc[0 + m2][q] + xr);
                float z = sigmoidf_(acc[2 + m2][q] + xz);
                float n = tanhf_(xn + r * (acc[4 + m2][q] + bhn[m2][q]));
                float hpv = d ? 0.0f : hp[m2][q];
                float hn2 = n + z * (hpv - n);
                hp[m2][q] = hn2;
                hnew4[q]  = hn2;
                hb[q] = f2bf(hn2);
            }
            *(f32x4*)(out_base + (size_t)t * BN_ * H_ + m2 * 16) = hnew4;
            const int j = jb + m2*16 + lg*4;    // j&7 in {0,4} -> 8B-aligned
            *(u16x4*)&hT[buf ^ 1][j >> 5][(j >> 3) & 3][lr][j & 7] = hb;
        }
        __syncthreads();
        buf ^= 1;
    }

    // final_h
    #pragma unroll
    for (int m2 = 0; m2 < 2; ++m2) {
        f32x4 hv;
        #pragma unroll
        for (int q = 0; q < 4; ++q) hv[q] = hp[m2][q];
        *(f32x4*)(out + (size_t)T_ * BN_ * H_ + (size_t)(bn0 + lr) * H_ + jb + m2*16 + lg*4) = hv;
    }
}

// ---------------------------------------------------------------------------
// Fallback (ws too small): round-1 fp32 VALU persistent kernel (correct, slow)
// ---------------------------------------------------------------------------
#define SPB 4
__global__ __launch_bounds__(256, 1)
void slotgru_fallback(const float* __restrict__ x, const int* __restrict__ dones,
                      const float* __restrict__ h0, const float* __restrict__ W_ih,
                      const float* __restrict__ W_hh, const float* __restrict__ b_ih,
                      const float* __restrict__ b_hh, float* __restrict__ out)
{
    __shared__ __align__(16) float xs[SPB][F_];
    __shared__ __align__(16) float hs[SPB][H_];
    const int j = threadIdx.x, bn0 = blockIdx.x * SPB;
    const float bi0 = b_ih[j], bi1 = b_ih[H_ + j], bi2 = b_ih[2*H_ + j];
    const float bh0 = b_hh[j], bh1 = b_hh[H_ + j], bh2 = b_hh[2*H_ + j];
    const float4* wi0 = (const float4*)(W_ih + (size_t)j * F_);
    const float4* wi1 = (const float4*)(W_ih + (size_t)(H_ + j) * F_);
    const float4* wi2 = (const float4*)(W_ih + (size_t)(2*H_ + j) * F_);
    const float4* wh0 = (const float4*)(W_hh + (size_t)j * H_);
    const float4* wh1 = (const float4*)(W_hh + (size_t)(H_ + j) * H_);
    const float4* wh2 = (const float4*)(W_hh + (size_t)(2*H_ + j) * H_);
    float hreg[SPB];
    #pragma unroll
    for (int s = 0; s < SPB; ++s) { float h = h0[(size_t)(bn0+s)*H_ + j]; hreg[s]=h; hs[s][j]=h; }
    for (int t = 0; t < T_; ++t) {
        int d[SPB];
        #pragma unroll
        for (int s = 0; s < SPB; ++s) d[s] = dones[(size_t)t*BN_ + bn0 + s];
        const float* xsrc = x + (size_t)((size_t)t*BN_ + bn0) * F_;
        ((float*)xs)[j] = xsrc[j]; ((float*)xs)[j+256] = xsrc[j+256];
        #pragma unroll
        for (int s = 0; s < SPB; ++s) if (d[s]) hs[s][j] = 0.0f;
        __syncthreads();
        float ax0[SPB]={0,0,0,0}, ax1[SPB]={0,0,0,0}, ax2[SPB]={0,0,0,0};
        #pragma unroll 8
        for (int c = 0; c < F_/4; ++c) {
            float4 w0=wi0[c], w1=wi1[c], w2=wi2[c];
            #pragma unroll
            for (int s = 0; s < SPB; ++s) {
                float4 xv = ((const float4*)xs[s])[c];
                ax0[s]=fmaf(w0.x,xv.x,fmaf(w0.y,xv.y,fmaf(w0.z,xv.z,fmaf(w0.w,xv.w,ax0[s]))));
                ax1[s]=fmaf(w1.x,xv.x,fmaf(w1.y,xv.y,fmaf(w1.z,xv.z,fmaf(w1.w,xv.w,ax1[s]))));
                ax2[s]=fmaf(w2.x,xv.x,fmaf(w2.y,xv.y,fmaf(w2.z,xv.z,fmaf(w2.w,xv.w,ax2[s]))));
            }
        }
        float ah0[SPB]={0,0,0,0}, ah1[SPB]={0,0,0,0}, ah2[SPB]={0,0,0,0};
        if (!(d[0]&&d[1]&&d[2]&&d[3])) {
            #pragma unroll 4
            for (int c = 0; c < H_/4; ++c) {
                float4 w0=wh0[c], w1=wh1[c], w2=wh2[c];
                #pragma unroll
                for (int s = 0; s < SPB; ++s) if (!d[s]) {
                    float4 hv = ((const float4*)hs[s])[c];
                    ah0[s]=fmaf(w0.x,hv.x,fmaf(w0.y,hv.y,fmaf(w0.z,hv.z,fmaf(w0.w,hv.w,ah0[s]))));
                    ah1[s]=fmaf(w1.x,hv.x,fmaf(w1.y,hv.y,fmaf(w1.z,hv.z,fmaf(w1.w,hv.w,ah1[s]))));
                    ah2[s]=fmaf(w2.x,hv.x,fmaf(w2.y,hv.y,fmaf(w2.z,hv.z,fmaf(w2.w,hv.w,ah2[s]))));
                }
            }
        }
        float hnew[SPB];
        #pragma unroll
        for (int s = 0; s < SPB; ++s) {
            float hpv = d[s] ? 0.0f : hreg[s];
            float r = sigmoidf_(ax0[s] + bi0 + ah0[s] + bh0);
            float z = sigmoidf_(ax1[s] + bi1 + ah1[s] + bh1);
            float n = tanhf_(ax2[s] + bi2 + r * (ah2[s] + bh2));
            hnew[s] = (1.0f - z) * n + z * hpv;
        }
        __syncthreads();
        #pragma unroll
        for (int s = 0; s < SPB; ++s) {
            hs[s][j] = hnew[s]; hreg[s] = hnew[s];
            out[(size_t)((size_t)t*BN_ + bn0 + s) * H_ + j] = hnew[s];
        }
    }
    #pragma unroll
    for (int s = 0; s < SPB; ++s)
        out[(size_t)T_*BN_*H_ + (size_t)(bn0+s)*H_ + j] = hreg[s];
}

extern "C" void kernel_launch(void* const* d_in, const int* in_sizes, int n_in,
                              void* d_out, int out_size, void* d_ws, size_t ws_size,
                              hipStream_t stream) {
    const float* x     = (const float*)d_in[0];
    const int*   dones = (const int*)  d_in[1];
    const float* h0    = (const float*)d_in[2];
    const float* W_ih  = (const float*)d_in[3];
    const float* W_hh  = (const float*)d_in[4];
    const float* b_ih  = (const float*)d_in[5];
    const float* b_hh  = (const float*)d_in[6];
    float*       out   = (float*)d_out;

    const size_t xg_bytes = (size_t)T_ * BN_ * G3_ * sizeof(unsigned short); // ~201 MB

    if (ws_size >= xg_bytes) {
        unsigned short* xg = (unsigned short*)d_ws;
        hipLaunchKernelGGL(xg_kernel, dim3((T_ * BN_) / 64), dim3(512), 0, stream,
                           x, W_ih, b_ih, b_hh, xg);
        hipLaunchKernelGGL(gru_kernel, dim3(BN_ / 16), dim3(512), 0, stream,
                           xg, dones, h0, W_hh, b_hh, out);
    } else {
        hipLaunchKernelGGL(slotgru_fallback, dim3(BN_ / SPB), dim3(256), 0, stream,
                           x, dones, h0, W_ih, W_hh, b_ih, b_hh, out);
    }
}

// Round 3
// 471.318 us; speedup vs baseline: 23.6855x; 2.8985x over previous
//
#include <hip/hip_runtime.h>
#include <math.h>

#define T_   256
#define B_   32
#define N_   16
#define F_   128
#define H_   256
#define BN_  512          // B*N
#define G3_  768          // 3*H
#define CL_  16           // chunk length
#define NC_  16           // number of chunks (T_/CL_)

typedef __attribute__((ext_vector_type(8))) short  bf16x8;
typedef __attribute__((ext_vector_type(4))) float  f32x4;
typedef __attribute__((ext_vector_type(4))) unsigned short u16x4;

// ---- workspace layout (bytes) ----
#define OFF_H1   0ULL                                   // f32 [NC][BN][H]   8 MB
#define OFF_HIN  8388608ULL                             // f32 [NC][BN][H]   8 MB
#define OFF_WBF  16777216ULL                            // bf16 [768][256]   384 KB
#define OFF_DM   17170432ULL                            // u16 [NC][BN]      16 KB
#define OFF_XG   17186816ULL                            // bf16 xg2 tiled    192 MB
#define WS_NEED  218513408ULL

__device__ __forceinline__ unsigned short f2bf(float f) {   // RNE float->bf16
    union { float f; unsigned u; } v; v.f = f;
    unsigned u = v.u + 0x7FFFu + ((v.u >> 16) & 1u);
    return (unsigned short)(u >> 16);
}
__device__ __forceinline__ float bf2f(unsigned short h) {
    union { unsigned u; float f; } v; v.u = ((unsigned)h) << 16;
    return v.f;
}
__device__ __forceinline__ bf16x8 load_pack8(const float* __restrict__ p) {
    f32x4 a = *(const f32x4*)p;
    f32x4 b = *(const f32x4*)(p + 4);
    bf16x8 r;
    r[0]=(short)f2bf(a[0]); r[1]=(short)f2bf(a[1]); r[2]=(short)f2bf(a[2]); r[3]=(short)f2bf(a[3]);
    r[4]=(short)f2bf(b[0]); r[5]=(short)f2bf(b[1]); r[6]=(short)f2bf(b[2]); r[7]=(short)f2bf(b[3]);
    return r;
}
__device__ __forceinline__ float sigmoidf_(float x) { return 1.0f / (1.0f + __expf(-x)); }
__device__ __forceinline__ float tanhf_(float x)    { return 1.0f - 2.0f / (__expf(2.0f * x) + 1.0f); }

// xg2 tiled layout: u16 index for element (tt, seq, g)
__device__ __forceinline__ size_t xg2_idx(int tt, int seq, int g) {
    return ((((size_t)tt * 32 + (seq >> 4)) * 48 + (g >> 4)) * 64
            + ((g >> 2) & 3) * 16 + (seq & 15)) * 4 + (g & 3);
}

// ---------------------------------------------------------------------------
// K0: prep — W_hh f32->bf16 ; dones -> per-(chunk,seq) 16-bit mask
// ---------------------------------------------------------------------------
__global__ __launch_bounds__(256)
void prep_kernel(const float* __restrict__ W_hh, const int* __restrict__ dones,
                 unsigned short* __restrict__ wbf, unsigned short* __restrict__ dm)
{
    const int bid = blockIdx.x, tid = threadIdx.x;
    if (bid < 192) {
        const int i4 = bid * 256 + tid;            // 49152 f32x4 units = 196608 elems
        f32x4 w = ((const f32x4*)W_hh)[i4];
        u16x4 o;
        #pragma unroll
        for (int q = 0; q < 4; ++q) o[q] = f2bf(w[q]);
        ((u16x4*)wbf)[i4] = o;
    } else {
        const int tg = (bid - 192) * 256 + tid;    // 8192 = NC*BN
        const int c = tg >> 9, s = tg & 511;
        unsigned m = 0;
        #pragma unroll
        for (int k = 0; k < CL_; ++k)
            m |= (dones[(c * CL_ + k) * BN_ + s] ? 1u : 0u) << k;
        dm[c * BN_ + s] = (unsigned short)m;
    }
}

// ---------------------------------------------------------------------------
// K1: xg2[t][seq][g] = bf16( x[t,seq,:]·W_ih[g,:] + b_ih[g] + (g<2H? b_hh[g]:0) )
// stored in consumer-tiled layout (coalesced writes via swapped MFMA operands).
// Block: 64 tb rows (one t, 64 seqs) × all 768 g. x staged via LDS as bf16.
// ---------------------------------------------------------------------------
__global__ __launch_bounds__(512, 2)
void xg2_kernel(const float* __restrict__ x, const float* __restrict__ W_ih,
                const float* __restrict__ b_ih, const float* __restrict__ b_hh,
                unsigned short* __restrict__ xg2)
{
    __shared__ __align__(16) unsigned short xls[64][136];   // 17408 B, +8 pad
    const int tid  = threadIdx.x;
    const int wave = tid >> 6, lane = tid & 63;
    const int lr = lane & 15, lg = lane >> 4;
    const int tb0 = blockIdx.x * 64;
    const int t   = tb0 >> 9;
    const int sb0 = (tb0 & 511) >> 4;
    const int g0  = wave * 96;

    // stage x tile -> bf16 LDS (coalesced f32x4 sweeps)
    #pragma unroll
    for (int sweep = 0; sweep < 4; ++sweep) {
        const int u = sweep * 512 + tid;           // f32x4 unit in [0,2048)
        f32x4 v = ((const f32x4*)x)[(size_t)tb0 * 32 + u];
        u16x4 o;
        #pragma unroll
        for (int q = 0; q < 4; ++q) o[q] = f2bf(v[q]);
        const int row = u >> 5, col4 = u & 31;
        *(u16x4*)&xls[row][col4 * 4] = o;
    }

    // A-fragments: W_ih rows (g), register-stationary
    bf16x8 wf[6][4];
    #pragma unroll
    for (int gt = 0; gt < 6; ++gt)
        #pragma unroll
        for (int kt = 0; kt < 4; ++kt)
            wf[gt][kt] = load_pack8(W_ih + (size_t)(g0 + gt*16 + lr) * F_ + kt*32 + lg*8);

    float bv[6][4];
    #pragma unroll
    for (int gt = 0; gt < 6; ++gt)
        #pragma unroll
        for (int q = 0; q < 4; ++q) {
            const int g = g0 + gt*16 + lg*4 + q;
            bv[gt][q] = b_ih[g] + (g < 2*H_ ? b_hh[g] : 0.0f);
        }

    __syncthreads();

    #pragma unroll
    for (int tbt = 0; tbt < 4; ++tbt) {
        bf16x8 xf[4];                              // B-fragments: x cols (tb)
        #pragma unroll
        for (int kt = 0; kt < 4; ++kt)
            xf[kt] = *(const bf16x8*)&xls[tbt*16 + lr][kt*32 + lg*8];

        f32x4 acc[6];
        #pragma unroll
        for (int gt = 0; gt < 6; ++gt) acc[gt] = (f32x4){0.f, 0.f, 0.f, 0.f};

        #pragma unroll
        for (int kt = 0; kt < 4; ++kt)
            #pragma unroll
            for (int gt = 0; gt < 6; ++gt)
                acc[gt] = __builtin_amdgcn_mfma_f32_16x16x32_bf16(wf[gt][kt], xf[kt], acc[gt], 0, 0, 0);

        // D: row = g-in-tile = lg*4+q, col = tb = lr  -> per-lane u16x4 unit,
        // store offset = lane*8B within the (t,sb,gtile) tile: fully coalesced.
        const int sb = sb0 + tbt;
        #pragma unroll
        for (int gt = 0; gt < 6; ++gt) {
            u16x4 o;
            #pragma unroll
            for (int q = 0; q < 4; ++q) o[q] = f2bf(acc[gt][q] + bv[gt][q]);
            const size_t base = (((size_t)t * 32 + sb) * 48 + (wave*6 + gt)) * 64 + lane;
            *(u16x4*)(xg2 + base * 4) = o;
        }
    }
}

// ---------------------------------------------------------------------------
// K2: pass1 — per (chunk, seq-group): run chunk from h=0 starting at the
// earliest last-done; h_end exact for every done-containing seq.
// ---------------------------------------------------------------------------
__global__ __launch_bounds__(512, 2)
void pass1_kernel(const unsigned short* __restrict__ xg2,
                  const unsigned short* __restrict__ dm,
                  const unsigned short* __restrict__ wbf,
                  const float* __restrict__ b_hh,
                  float* __restrict__ h1)
{
    __shared__ __align__(16) unsigned short hT[2][8][4][16][8];   // 16 KB
    const int tid  = threadIdx.x;
    const int wave = tid >> 6, lane = tid & 63;
    const int lr = lane & 15, lg = lane >> 4;
    const int c   = blockIdx.x >> 5;            // 0..14
    const int bn0 = (blockIdx.x & 31) * 16;
    const int jb  = wave * 32;

    const unsigned m = dm[c * BN_ + bn0 + lr];
    if (__ballot(m != 0) == 0ULL) return;       // no dones anywhere: h1 unused

    int last = m ? (31 - __builtin_clz(m)) : 15;
    #pragma unroll
    for (int w = 1; w < 16; w <<= 1) last = min(last, __shfl_xor(last, w));

    // register-stationary W_hh (bf16, direct u16x8 loads)
    bf16x8 wf[6][8];
    #pragma unroll
    for (int mt = 0; mt < 6; ++mt) {
        const int row = (mt >> 1) * H_ + jb + (mt & 1) * 16 + lr;
        #pragma unroll
        for (int kt = 0; kt < 8; ++kt)
            wf[mt][kt] = *(const bf16x8*)(wbf + (size_t)row * H_ + kt*32 + lg*8);
    }
    float bhn[2][4], hp[2][4];
    #pragma unroll
    for (int m2 = 0; m2 < 2; ++m2)
        #pragma unroll
        for (int q = 0; q < 4; ++q) {
            bhn[m2][q] = b_hh[2*H_ + jb + m2*16 + lg*4 + q];
            hp[m2][q]  = 0.0f;
        }

    // zero h state
    {
        bf16x8 z = (bf16x8)(short)0;
        *(bf16x8*)((unsigned short*)hT + (size_t)tid * 16) = z;
        *(bf16x8*)((unsigned short*)hT + (size_t)tid * 16 + 8) = z;
    }
    __syncthreads();

    int buf = 0;
    for (int t = last; t < CL_; ++t) {
        const int tt = c * CL_ + t;
        // coalesced xv loads (512B/wave/inst)
        u16x4 xv[3][2];
        #pragma unroll
        for (int gate = 0; gate < 3; ++gate)
            #pragma unroll
            for (int m2 = 0; m2 < 2; ++m2) {
                const size_t base = (((size_t)tt * 32 + (bn0 >> 4)) * 48
                                     + gate*16 + wave*2 + m2) * 64 + lane;
                xv[gate][m2] = *(const u16x4*)(xg2 + base * 4);
            }

        const int d = (m >> t) & 1;
        const short dms = (short)(d ? 0 : -1);

        f32x4 acc[6];
        #pragma unroll
        for (int mt = 0; mt < 6; ++mt) acc[mt] = (f32x4){0.f, 0.f, 0.f, 0.f};
        #pragma unroll
        for (int kt = 0; kt < 8; ++kt) {
            bf16x8 hv = *(const bf16x8*)&hT[buf][kt][lg][lr][0];
            hv = hv & dms;
            #pragma unroll
            for (int mt = 0; mt < 6; ++mt)
                acc[mt] = __builtin_amdgcn_mfma_f32_16x16x32_bf16(wf[mt][kt], hv, acc[mt], 0, 0, 0);
        }

        #pragma unroll
        for (int m2 = 0; m2 < 2; ++m2) {
            u16x4 hb;
            #pragma unroll
            for (int q = 0; q < 4; ++q) {
                float r = sigmoidf_(acc[0 + m2][q] + bf2f(xv[0][m2][q]));
                float z = sigmoidf_(acc[2 + m2][q] + bf2f(xv[1][m2][q]));
                float n = tanhf_(bf2f(xv[2][m2][q]) + r * (acc[4 + m2][q] + bhn[m2][q]));
                float hpv = d ? 0.0f : hp[m2][q];
                float hn2 = n + z * (hpv - n);
                hp[m2][q] = hn2;
                hb[q] = f2bf(hn2);
            }
            const int j = jb + m2*16 + lg*4;
            *(u16x4*)&hT[buf ^ 1][j >> 5][(j >> 3) & 3][lr][j & 7] = hb;
        }
        __syncthreads();
        buf ^= 1;
    }

    #pragma unroll
    for (int m2 = 0; m2 < 2; ++m2) {
        f32x4 hv;
        #pragma unroll
        for (int q = 0; q < 4; ++q) hv[q] = hp[m2][q];
        *(f32x4*)(h1 + ((size_t)c * BN_ + bn0 + lr) * H_ + jb + m2*16 + lg*4) = hv;
    }
}

// ---------------------------------------------------------------------------
// K3: pass2 — chain h_in across chunks per seq. Copy when chunk has a done;
// rare VALU GRU for transparent chunks (no dones inside, by definition).
// ---------------------------------------------------------------------------
__global__ __launch_bounds__(256)
void pass2_kernel(const unsigned short* __restrict__ xg2,
                  const unsigned short* __restrict__ dm,
                  const unsigned short* __restrict__ wbf,
                  const float* __restrict__ b_hh,
                  const float* __restrict__ h0,
                  const float* __restrict__ h1,
                  float* __restrict__ hin)
{
    __shared__ unsigned short hsb[H_];
    const int s = blockIdx.x, j = threadIdx.x;
    float h = h0[(size_t)s * H_ + j];
    const float bhn = b_hh[2*H_ + j];

    for (int c = 0; c < NC_; ++c) {
        hin[((size_t)c * BN_ + s) * H_ + j] = h;
        if (c == NC_ - 1) break;
        const unsigned short m = dm[c * BN_ + s];   // block-uniform
        if (m) {
            h = h1[((size_t)c * BN_ + s) * H_ + j];
        } else {
            for (int t = 0; t < CL_; ++t) {
                hsb[j] = f2bf(h);
                __syncthreads();
                float a0 = 0.f, a1 = 0.f, a2 = 0.f;
                for (int k = 0; k < H_; ++k) {
                    float hk = bf2f(hsb[k]);
                    a0 = fmaf(bf2f(wbf[(size_t)j * H_ + k]),          hk, a0);
                    a1 = fmaf(bf2f(wbf[(size_t)(H_ + j) * H_ + k]),   hk, a1);
                    a2 = fmaf(bf2f(wbf[(size_t)(2*H_ + j) * H_ + k]), hk, a2);
                }
                const int tt = c * CL_ + t;
                float xr = bf2f(xg2[xg2_idx(tt, s, j)]);
                float xz = bf2f(xg2[xg2_idx(tt, s, H_ + j)]);
                float xn = bf2f(xg2[xg2_idx(tt, s, 2*H_ + j)]);
                float r = sigmoidf_(a0 + xr);
                float z = sigmoidf_(a1 + xz);
                float n = tanhf_(xn + r * (a2 + bhn));
                h = n + z * (h - n);
                __syncthreads();
            }
        }
    }
}

// ---------------------------------------------------------------------------
// K4: pass3 — per (chunk, seq-group): from known h_in, compute all outputs.
// ---------------------------------------------------------------------------
__global__ __launch_bounds__(512, 2)
void pass3_kernel(const unsigned short* __restrict__ xg2,
                  const unsigned short* __restrict__ dm,
                  const unsigned short* __restrict__ wbf,
                  const float* __restrict__ b_hh,
                  const float* __restrict__ hin,
                  float* __restrict__ out)
{
    __shared__ __align__(16) unsigned short hT[2][8][4][16][8];   // 16 KB
    const int tid  = threadIdx.x;
    const int wave = tid >> 6, lane = tid & 63;
    const int lr = lane & 15, lg = lane >> 4;
    const int c   = blockIdx.x >> 5;            // 0..15
    const int bn0 = (blockIdx.x & 31) * 16;
    const int jb  = wave * 32;

    const unsigned m = dm[c * BN_ + bn0 + lr];

    bf16x8 wf[6][8];
    #pragma unroll
    for (int mt = 0; mt < 6; ++mt) {
        const int row = (mt >> 1) * H_ + jb + (mt & 1) * 16 + lr;
        #pragma unroll
        for (int kt = 0; kt < 8; ++kt)
            wf[mt][kt] = *(const bf16x8*)(wbf + (size_t)row * H_ + kt*32 + lg*8);
    }
    float bhn[2][4], hp[2][4];
    #pragma unroll
    for (int m2 = 0; m2 < 2; ++m2)
        #pragma unroll
        for (int q = 0; q < 4; ++q) {
            const int j = jb + m2*16 + lg*4 + q;
            bhn[m2][q] = b_hh[2*H_ + j];
        }
    {
        // hp regs from hin (f32)
        #pragma unroll
        for (int m2 = 0; m2 < 2; ++m2) {
            f32x4 hv = *(const f32x4*)(hin + ((size_t)c * BN_ + bn0 + lr) * H_ + jb + m2*16 + lg*4);
            #pragma unroll
            for (int q = 0; q < 4; ++q) hp[m2][q] = hv[q];
        }
        // stage h_in -> hT[0] (bf16)
        const int col = tid & 15, kb = (tid >> 4) * 8;
        bf16x8 hv = load_pack8(hin + ((size_t)c * BN_ + bn0 + col) * H_ + kb);
        *(bf16x8*)((unsigned short*)hT + (size_t)tid * 8) = hv;
    }
    __syncthreads();

    float* out_base = out + (size_t)(bn0 + lr) * H_ + jb + lg*4;

    int buf = 0;
    for (int t = 0; t < CL_; ++t) {
        const int tt = c * CL_ + t;
        u16x4 xv[3][2];
        #pragma unroll
        for (int gate = 0; gate < 3; ++gate)
            #pragma unroll
            for (int m2 = 0; m2 < 2; ++m2) {
                const size_t base = (((size_t)tt * 32 + (bn0 >> 4)) * 48
                                     + gate*16 + wave*2 + m2) * 64 + lane;
                xv[gate][m2] = *(const u16x4*)(xg2 + base * 4);
            }

        const int d = (m >> t) & 1;
        const short dms = (short)(d ? 0 : -1);

        f32x4 acc[6];
        #pragma unroll
        for (int mt = 0; mt < 6; ++mt) acc[mt] = (f32x4){0.f, 0.f, 0.f, 0.f};
        #pragma unroll
        for (int kt = 0; kt < 8; ++kt) {
            bf16x8 hv = *(const bf16x8*)&hT[buf][kt][lg][lr][0];
            hv = hv & dms;
            #pragma unroll
            for (int mt = 0; mt < 6; ++mt)
                acc[mt] = __builtin_amdgcn_mfma_f32_16x16x32_bf16(wf[mt][kt], hv, acc[mt], 0, 0, 0);
        }

        f32x4 hnew4[2];
        #pragma unroll
        for (int m2 = 0; m2 < 2; ++m2) {
            u16x4 hb;
            #pragma unroll
            for (int q = 0; q < 4; ++q) {
                float r = sigmoidf_(acc[0 + m2][q] + bf2f(xv[0][m2][q]));
                float z = sigmoidf_(acc[2 + m2][q] + bf2f(xv[1][m2][q]));
                float n = tanhf_(bf2f(xv[2][m2][q]) + r * (acc[4 + m2][q] + bhn[m2][q]));
                float hpv = d ? 0.0f : hp[m2][q];
                float hn2 = n + z * (hpv - n);
                hp[m2][q] = hn2;
                hnew4[m2][q] = hn2;
                hb[q] = f2bf(hn2);
            }
            const int j = jb + m2*16 + lg*4;
            *(u16x4*)&hT[buf ^ 1][j >> 5][(j >> 3) & 3][lr][j & 7] = hb;
        }
        __syncthreads();
        // out stores after the barrier: their drain overlaps the next step
        #pragma unroll
        for (int m2 = 0; m2 < 2; ++m2)
            *(f32x4*)(out_base + (size_t)tt * BN_ * H_ + m2 * 16) = hnew4[m2];
        buf ^= 1;
    }

    if (c == NC_ - 1) {
        #pragma unroll
        for (int m2 = 0; m2 < 2; ++m2) {
            f32x4 hv;
            #pragma unroll
            for (int q = 0; q < 4; ++q) hv[q] = hp[m2][q];
            *(f32x4*)(out + (size_t)T_ * BN_ * H_ + (size_t)(bn0 + lr) * H_ + jb + m2*16 + lg*4) = hv;
        }
    }
}

// ---------------------------------------------------------------------------
// Fallback (ws too small): fp32 VALU persistent kernel (correct, slow)
// ---------------------------------------------------------------------------
#define SPB 4
__global__ __launch_bounds__(256, 1)
void slotgru_fallback(const float* __restrict__ x, const int* __restrict__ dones,
                      const float* __restrict__ h0, const float* __restrict__ W_ih,
                      const float* __restrict__ W_hh, const float* __restrict__ b_ih,
                      const float* __restrict__ b_hh, float* __restrict__ out)
{
    __shared__ __align__(16) float xs[SPB][F_];
    __shared__ __align__(16) float hs[SPB][H_];
    const int j = threadIdx.x, bn0 = blockIdx.x * SPB;
    const float bi0 = b_ih[j], bi1 = b_ih[H_ + j], bi2 = b_ih[2*H_ + j];
    const float bh0 = b_hh[j], bh1 = b_hh[H_ + j], bh2 = b_hh[2*H_ + j];
    const float4* wi0 = (const float4*)(W_ih + (size_t)j * F_);
    const float4* wi1 = (const float4*)(W_ih + (size_t)(H_ + j) * F_);
    const float4* wi2 = (const float4*)(W_ih + (size_t)(2*H_ + j) * F_);
    const float4* wh0 = (const float4*)(W_hh + (size_t)j * H_);
    const float4* wh1 = (const float4*)(W_hh + (size_t)(H_ + j) * H_);
    const float4* wh2 = (const float4*)(W_hh + (size_t)(2*H_ + j) * H_);
    float hreg[SPB];
    #pragma unroll
    for (int s = 0; s < SPB; ++s) { float h = h0[(size_t)(bn0+s)*H_ + j]; hreg[s]=h; hs[s][j]=h; }
    for (int t = 0; t < T_; ++t) {
        int d[SPB];
        #pragma unroll
        for (int s = 0; s < SPB; ++s) d[s] = dones[(size_t)t*BN_ + bn0 + s];
        const float* xsrc = x + (size_t)((size_t)t*BN_ + bn0) * F_;
        ((float*)xs)[j] = xsrc[j]; ((float*)xs)[j+256] = xsrc[j+256];
        #pragma unroll
        for (int s = 0; s < SPB; ++s) if (d[s]) hs[s][j] = 0.0f;
        __syncthreads();
        float ax0[SPB]={0,0,0,0}, ax1[SPB]={0,0,0,0}, ax2[SPB]={0,0,0,0};
        #pragma unroll 8
        for (int cc = 0; cc < F_/4; ++cc) {
            float4 w0=wi0[cc], w1=wi1[cc], w2=wi2[cc];
            #pragma unroll
            for (int s = 0; s < SPB; ++s) {
                float4 xv = ((const float4*)xs[s])[cc];
                ax0[s]=fmaf(w0.x,xv.x,fmaf(w0.y,xv.y,fmaf(w0.z,xv.z,fmaf(w0.w,xv.w,ax0[s]))));
                ax1[s]=fmaf(w1.x,xv.x,fmaf(w1.y,xv.y,fmaf(w1.z,xv.z,fmaf(w1.w,xv.w,ax1[s]))));
                ax2[s]=fmaf(w2.x,xv.x,fmaf(w2.y,xv.y,fmaf(w2.z,xv.z,fmaf(w2.w,xv.w,ax2[s]))));
            }
        }
        float ah0[SPB]={0,0,0,0}, ah1[SPB]={0,0,0,0}, ah2[SPB]={0,0,0,0};
        if (!(d[0]&&d[1]&&d[2]&&d[3])) {
            #pragma unroll 4
            for (int cc = 0; cc < H_/4; ++cc) {
                float4 w0=wh0[cc], w1=wh1[cc], w2=wh2[cc];
                #pragma unroll
                for (int s = 0; s < SPB; ++s) if (!d[s]) {
                    float4 hv = ((const float4*)hs[s])[cc];
                    ah0[s]=fmaf(w0.x,hv.x,fmaf(w0.y,hv.y,fmaf(w0.z,hv.z,fmaf(w0.w,hv.w,ah0[s]))));
                    ah1[s]=fmaf(w1.x,hv.x,fmaf(w1.y,hv.y,fmaf(w1.z,hv.z,fmaf(w1.w,hv.w,ah1[s]))));
                    ah2[s]=fmaf(w2.x,hv.x,fmaf(w2.y,hv.y,fmaf(w2.z,hv.z,fmaf(w2.w,hv.w,ah2[s]))));
                }
            }
        }
        float hnew[SPB];
        #pragma unroll
        for (int s = 0; s < SPB; ++s) {
            float hpv = d[s] ? 0.0f : hreg[s];
            float r = sigmoidf_(ax0[s] + bi0 + ah0[s] + bh0);
            float z = sigmoidf_(ax1[s] + bi1 + ah1[s] + bh1);
            float n = tanhf_(ax2[s] + bi2 + r * (ah2[s] + bh2));
            hnew[s] = (1.0f - z) * n + z * hpv;
        }
        __syncthreads();
        #pragma unroll
        for (int s = 0; s < SPB; ++s) {
            hs[s][j] = hnew[s]; hreg[s] = hnew[s];
            out[(size_t)((size_t)t*BN_ + bn0 + s) * H_ + j] = hnew[s];
        }
    }
    #pragma unroll
    for (int s = 0; s < SPB; ++s)
        out[(size_t)T_*BN_*H_ + (size_t)(bn0+s)*H_ + j] = hreg[s];
}

extern "C" void kernel_launch(void* const* d_in, const int* in_sizes, int n_in,
                              void* d_out, int out_size, void* d_ws, size_t ws_size,
                              hipStream_t stream) {
    const float* x     = (const float*)d_in[0];
    const int*   dones = (const int*)  d_in[1];
    const float* h0    = (const float*)d_in[2];
    const float* W_ih  = (const float*)d_in[3];
    const float* W_hh  = (const float*)d_in[4];
    const float* b_ih  = (const float*)d_in[5];
    const float* b_hh  = (const float*)d_in[6];
    float*       out   = (float*)d_out;

    if (ws_size >= WS_NEED) {
        char* ws = (char*)d_ws;
        float*          h1  = (float*)(ws + OFF_H1);
        float*          hin = (float*)(ws + OFF_HIN);
        unsigned short* wbf = (unsigned short*)(ws + OFF_WBF);
        unsigned short* dmm = (unsigned short*)(ws + OFF_DM);
        unsigned short* xg2 = (unsigned short*)(ws + OFF_XG);

        hipLaunchKernelGGL(prep_kernel, dim3(224), dim3(256), 0, stream,
                           W_hh, dones, wbf, dmm);
        hipLaunchKernelGGL(xg2_kernel, dim3((T_ * BN_) / 64), dim3(512), 0, stream,
                           x, W_ih, b_ih, b_hh, xg2);
        hipLaunchKernelGGL(pass1_kernel, dim3((NC_ - 1) * 32), dim3(512), 0, stream,
                           xg2, dmm, wbf, b_hh, h1);
        hipLaunchKernelGGL(pass2_kernel, dim3(BN_), dim3(256), 0, stream,
                           xg2, dmm, wbf, b_hh, h0, h1, hin);
        hipLaunchKernelGGL(pass3_kernel, dim3(NC_ * 32), dim3(512), 0, stream,
                           xg2, dmm, wbf, b_hh, hin, out);
    } else {
        hipLaunchKernelGGL(slotgru_fallback, dim3(BN_ / SPB), dim3(256), 0, stream,
                           x, dones, h0, W_ih, W_hh, b_ih, b_hh, out);
    }
}

// Round 4
// 393.613 us; speedup vs baseline: 28.3614x; 1.1974x over previous
//
#include <hip/hip_runtime.h>
#include <math.h>

#define T_   256
#define B_   32
#define N_   16
#define F_   128
#define H_   256
#define BN_  512          // B*N
#define G3_  768          // 3*H
#define CL_  32           // chunk length
#define NC_  8            // number of chunks (T_/CL_)

typedef __attribute__((ext_vector_type(8))) short  bf16x8;
typedef __attribute__((ext_vector_type(4))) float  f32x4;
typedef __attribute__((ext_vector_type(4))) unsigned short u16x4;

// ---- workspace layout (bytes) ----
#define OFF_H1   0ULL                                   // f32 [NC][BN][H]   4 MB
#define OFF_HIN  4194304ULL                             // f32 [NC][BN][H]   4 MB
#define OFF_WBF  8388608ULL                             // bf16 [768][256]   384 KB
#define OFF_DM   8781824ULL                             // u32 [NC][BN]      16 KB
#define OFF_XG   8798208ULL                             // bf16 xg2 tiled    192 MB
#define WS_NEED  210124800ULL

__device__ __forceinline__ unsigned short f2bf(float f) {   // RNE float->bf16
    union { float f; unsigned u; } v; v.f = f;
    unsigned u = v.u + 0x7FFFu + ((v.u >> 16) & 1u);
    return (unsigned short)(u >> 16);
}
__device__ __forceinline__ float bf2f(unsigned short h) {
    union { unsigned u; float f; } v; v.u = ((unsigned)h) << 16;
    return v.f;
}
__device__ __forceinline__ bf16x8 load_pack8(const float* __restrict__ p) {
    f32x4 a = *(const f32x4*)p;
    f32x4 b = *(const f32x4*)(p + 4);
    bf16x8 r;
    r[0]=(short)f2bf(a[0]); r[1]=(short)f2bf(a[1]); r[2]=(short)f2bf(a[2]); r[3]=(short)f2bf(a[3]);
    r[4]=(short)f2bf(b[0]); r[5]=(short)f2bf(b[1]); r[6]=(short)f2bf(b[2]); r[7]=(short)f2bf(b[3]);
    return r;
}
__device__ __forceinline__ float sigmoidf_(float x) { return 1.0f / (1.0f + __expf(-x)); }
__device__ __forceinline__ float tanhf_(float x)    { return 1.0f - 2.0f / (__expf(2.0f * x) + 1.0f); }

// xg2 tiled layout: u16 index for element (tt, seq, g)
__device__ __forceinline__ size_t xg2_idx(int tt, int seq, int g) {
    return ((((size_t)tt * 32 + (seq >> 4)) * 48 + (g >> 4)) * 64
            + ((g >> 2) & 3) * 16 + (seq & 15)) * 4 + (g & 3);
}

// ---------------------------------------------------------------------------
// K1: xg2 GEMM (blocks < 2048) + fused prep (blocks >= 2048):
//     wbf = bf16(W_hh); dm = 32-bit done mask per (chunk, seq)
// ---------------------------------------------------------------------------
__global__ __launch_bounds__(512, 2)
void xg2_kernel(const float* __restrict__ x, const float* __restrict__ W_ih,
                const float* __restrict__ b_ih, const float* __restrict__ b_hh,
                const float* __restrict__ W_hh, const int* __restrict__ dones,
                unsigned short* __restrict__ xg2,
                unsigned short* __restrict__ wbf, unsigned int* __restrict__ dm)
{
    const int tid = threadIdx.x;
    if (blockIdx.x >= 2048) {                       // ---- fused prep ----
        const int bid2 = blockIdx.x - 2048;
        if (bid2 < 96) {                            // W_hh f32 -> bf16
            const int i4 = bid2 * 512 + tid;        // 49152 f32x4 units
            f32x4 w = ((const f32x4*)W_hh)[i4];
            u16x4 o;
            #pragma unroll
            for (int q = 0; q < 4; ++q) o[q] = f2bf(w[q]);
            ((u16x4*)wbf)[i4] = o;
        } else {                                    // done masks (u32, CL=32)
            const int u = (bid2 - 96) * 512 + tid;  // 4096 = NC*BN
            const int c = u >> 9, s = u & 511;
            unsigned m = 0;
            #pragma unroll
            for (int k = 0; k < CL_; ++k)
                m |= (dones[(c * CL_ + k) * BN_ + s] ? 1u : 0u) << k;
            dm[c * BN_ + s] = m;
        }
        return;
    }

    __shared__ __align__(16) unsigned short xls[64][136];   // 17408 B, +8 pad
    const int wave = tid >> 6, lane = tid & 63;
    const int lr = lane & 15, lg = lane >> 4;
    const int tb0 = blockIdx.x * 64;
    const int t   = tb0 >> 9;
    const int sb0 = (tb0 & 511) >> 4;
    const int g0  = wave * 96;

    // stage x tile -> bf16 LDS (coalesced f32x4 sweeps)
    #pragma unroll
    for (int sweep = 0; sweep < 4; ++sweep) {
        const int u = sweep * 512 + tid;
        f32x4 v = ((const f32x4*)x)[(size_t)tb0 * 32 + u];
        u16x4 o;
        #pragma unroll
        for (int q = 0; q < 4; ++q) o[q] = f2bf(v[q]);
        const int row = u >> 5, col4 = u & 31;
        *(u16x4*)&xls[row][col4 * 4] = o;
    }

    bf16x8 wf[6][4];
    #pragma unroll
    for (int gt = 0; gt < 6; ++gt)
        #pragma unroll
        for (int kt = 0; kt < 4; ++kt)
            wf[gt][kt] = load_pack8(W_ih + (size_t)(g0 + gt*16 + lr) * F_ + kt*32 + lg*8);

    float bv[6][4];
    #pragma unroll
    for (int gt = 0; gt < 6; ++gt)
        #pragma unroll
        for (int q = 0; q < 4; ++q) {
            const int g = g0 + gt*16 + lg*4 + q;
            bv[gt][q] = b_ih[g] + (g < 2*H_ ? b_hh[g] : 0.0f);
        }

    __syncthreads();

    #pragma unroll
    for (int tbt = 0; tbt < 4; ++tbt) {
        bf16x8 xf[4];
        #pragma unroll
        for (int kt = 0; kt < 4; ++kt)
            xf[kt] = *(const bf16x8*)&xls[tbt*16 + lr][kt*32 + lg*8];

        f32x4 acc[6];
        #pragma unroll
        for (int gt = 0; gt < 6; ++gt) acc[gt] = (f32x4){0.f, 0.f, 0.f, 0.f};

        #pragma unroll
        for (int kt = 0; kt < 4; ++kt)
            #pragma unroll
            for (int gt = 0; gt < 6; ++gt)
                acc[gt] = __builtin_amdgcn_mfma_f32_16x16x32_bf16(wf[gt][kt], xf[kt], acc[gt], 0, 0, 0);

        const int sb = sb0 + tbt;
        #pragma unroll
        for (int gt = 0; gt < 6; ++gt) {
            u16x4 o;
            #pragma unroll
            for (int q = 0; q < 4; ++q) o[q] = f2bf(acc[gt][q] + bv[gt][q]);
            const size_t base = (((size_t)t * 32 + sb) * 48 + (wave*6 + gt)) * 64 + lane;
            *(u16x4*)(xg2 + base * 4) = o;
        }
    }
}

// ---------------------------------------------------------------------------
// Recurrent core: 256 threads = 4 waves, 1 block/CU, 1 wave/SIMD.
// Wave w owns j in [64w, 64w+64): 12 m-tiles x 8 k-tiles of W_hh held
// register-stationary (384 VGPR). h_prev f32 + hT bf16 ping-pong in LDS.
// ---------------------------------------------------------------------------
__global__ __launch_bounds__(256, 1)
void pass1_kernel(const unsigned short* __restrict__ xg2,
                  const unsigned int*  __restrict__ dm,
                  const unsigned short* __restrict__ wbf,
                  const float* __restrict__ b_hh,
                  float* __restrict__ h1)
{
    __shared__ __align__(16) unsigned short hT[2][8][4][16][8];   // 16 KB
    __shared__ __align__(16) float hpL[16][260];                  // 16.6 KB
    __shared__ float bhnL[H_];                                    // 1 KB

    const int tid  = threadIdx.x;
    const int wave = tid >> 6, lane = tid & 63;
    const int lr = lane & 15, lg = lane >> 4;
    const int c   = blockIdx.x >> 5;            // 0..NC_-2
    const int bn0 = (blockIdx.x & 31) * 16;
    const int jb  = wave * 64;

    const unsigned m = dm[c * BN_ + bn0 + lr];
    if (__ballot(m != 0) == 0ULL) return;       // whole group transparent

    int last = m ? (31 - __builtin_clz(m)) : 31;
    #pragma unroll
    for (int w = 1; w < 16; w <<= 1) last = min(last, __shfl_xor(last, w));

    bhnL[tid] = b_hh[2*H_ + tid];
    // zero h state (bf16 + f32)
    #pragma unroll
    for (int sweep = 0; sweep < 2; ++sweep)
        ((bf16x8*)hT)[sweep * 256 + tid] = (bf16x8)(short)0;
    #pragma unroll
    for (int sweep = 0; sweep < 4; ++sweep) {
        const int u = sweep * 256 + tid, seq = u >> 6, jq = u & 63;
        *(f32x4*)&hpL[seq][jq * 4] = (f32x4){0.f, 0.f, 0.f, 0.f};
    }

    // register-stationary W_hh: 12 m-tiles (3 gates x 4 j-subtiles) x 8 kt
    bf16x8 wf[12][8];
    #pragma unroll
    for (int g = 0; g < 3; ++g)
        #pragma unroll
        for (int ms = 0; ms < 4; ++ms) {
            const int row = g * H_ + jb + ms * 16 + lr;
            #pragma unroll
            for (int kt = 0; kt < 8; ++kt)
                wf[g*4 + ms][kt] = *(const bf16x8*)(wbf + (size_t)row * H_ + kt*32 + lg*8);
        }
    __syncthreads();

    const int sb = bn0 >> 4;
    int buf = 0;
    for (int t = last; t < CL_; ++t) {
        const int tt = c * CL_ + t;
        const int tb = (tt * 32 + sb) * 48;

        u16x4 xv[3][4];
        #pragma unroll
        for (int g = 0; g < 3; ++g)
            #pragma unroll
            for (int ms = 0; ms < 4; ++ms)
                xv[g][ms] = ((const u16x4*)xg2)[(tb + g*16 + wave*4 + ms) * 64 + lane];

        const int d = (m >> t) & 1;
        const short dms = (short)(d ? 0 : -1);

        f32x4 acc[12];
        #pragma unroll
        for (int mt = 0; mt < 8; ++mt) acc[mt] = (f32x4){0.f, 0.f, 0.f, 0.f};
        #pragma unroll
        for (int ms = 0; ms < 4; ++ms)                 // n-gate seeded with b_hh_n
            acc[8 + ms] = *(const f32x4*)&bhnL[jb + ms*16 + lg*4];

        #pragma unroll
        for (int kt = 0; kt < 8; ++kt) {
            bf16x8 hv = *(const bf16x8*)&hT[buf][kt][lg][lr][0];
            hv = hv & dms;
            #pragma unroll
            for (int mt = 0; mt < 12; ++mt)
                acc[mt] = __builtin_amdgcn_mfma_f32_16x16x32_bf16(wf[mt][kt], hv, acc[mt], 0, 0, 0);
        }

        #pragma unroll
        for (int ms = 0; ms < 4; ++ms) {
            const int jq = jb + ms*16 + lg*4;
            f32x4 hp4 = *(const f32x4*)&hpL[lr][jq];
            f32x4 hnew4; u16x4 hb;
            #pragma unroll
            for (int q = 0; q < 4; ++q) {
                float r = sigmoidf_(acc[0 + ms][q] + bf2f(xv[0][ms][q]));
                float z = sigmoidf_(acc[4 + ms][q] + bf2f(xv[1][ms][q]));
                float n = tanhf_(bf2f(xv[2][ms][q]) + r * acc[8 + ms][q]);
                float hpv = d ? 0.0f : hp4[q];
                float hn2 = n + z * (hpv - n);
                hnew4[q] = hn2; hb[q] = f2bf(hn2);
            }
            *(f32x4*)&hpL[lr][jq] = hnew4;
            *(u16x4*)&hT[buf ^ 1][jq >> 5][(jq >> 3) & 3][lr][jq & 7] = hb;
        }
        __syncthreads();
        buf ^= 1;
    }

    #pragma unroll
    for (int ms = 0; ms < 4; ++ms) {
        const int jq = jb + ms*16 + lg*4;
        f32x4 hv = *(const f32x4*)&hpL[lr][jq];
        *(f32x4*)(h1 + ((size_t)c * BN_ + bn0 + lr) * H_ + jq) = hv;
    }
}

// ---------------------------------------------------------------------------
// pass2: chain h across chunks. Copy when chunk has a done; rare VALU GRU.
// ---------------------------------------------------------------------------
__global__ __launch_bounds__(256)
void pass2_kernel(const unsigned short* __restrict__ xg2,
                  const unsigned int*  __restrict__ dm,
                  const unsigned short* __restrict__ wbf,
                  const float* __restrict__ b_hh,
                  const float* __restrict__ h0,
                  const float* __restrict__ h1,
                  float* __restrict__ hin)
{
    __shared__ unsigned short hsb[H_];
    const int s = blockIdx.x, j = threadIdx.x;
    float h = h0[(size_t)s * H_ + j];
    const float bhn = b_hh[2*H_ + j];

    for (int c = 0; c < NC_; ++c) {
        hin[((size_t)c * BN_ + s) * H_ + j] = h;
        if (c == NC_ - 1) break;
        const unsigned m = dm[c * BN_ + s];         // block-uniform
        if (m) {
            h = h1[((size_t)c * BN_ + s) * H_ + j];
        } else {
            for (int t = 0; t < CL_; ++t) {
                hsb[j] = f2bf(h);
                __syncthreads();
                float a0 = 0.f, a1 = 0.f, a2 = 0.f;
                for (int k = 0; k < H_; ++k) {
                    float hk = bf2f(hsb[k]);
                    a0 = fmaf(bf2f(wbf[(size_t)j * H_ + k]),          hk, a0);
                    a1 = fmaf(bf2f(wbf[(size_t)(H_ + j) * H_ + k]),   hk, a1);
                    a2 = fmaf(bf2f(wbf[(size_t)(2*H_ + j) * H_ + k]), hk, a2);
                }
                const int tt = c * CL_ + t;
                float xr = bf2f(xg2[xg2_idx(tt, s, j)]);
                float xz = bf2f(xg2[xg2_idx(tt, s, H_ + j)]);
                float xn = bf2f(xg2[xg2_idx(tt, s, 2*H_ + j)]);
                float r = sigmoidf_(a0 + xr);
                float z = sigmoidf_(a1 + xz);
                float n = tanhf_(xn + r * (a2 + bhn));
                h = n + z * (h - n);
                __syncthreads();
            }
        }
    }
}

// ---------------------------------------------------------------------------
// pass3: from known h_in, compute all outputs. Same core as pass1 + out stores.
// ---------------------------------------------------------------------------
__global__ __launch_bounds__(256, 1)
void pass3_kernel(const unsigned short* __restrict__ xg2,
                  const unsigned int*  __restrict__ dm,
                  const unsigned short* __restrict__ wbf,
                  const float* __restrict__ b_hh,
                  const float* __restrict__ hin,
                  float* __restrict__ out)
{
    __shared__ __align__(16) unsigned short hT[2][8][4][16][8];   // 16 KB
    __shared__ __align__(16) float hpL[16][260];                  // 16.6 KB
    __shared__ float bhnL[H_];                                    // 1 KB

    const int tid  = threadIdx.x;
    const int wave = tid >> 6, lane = tid & 63;
    const int lr = lane & 15, lg = lane >> 4;
    const int c   = blockIdx.x >> 5;            // 0..NC_-1
    const int bn0 = (blockIdx.x & 31) * 16;
    const int jb  = wave * 64;

    const unsigned m = dm[c * BN_ + bn0 + lr];

    bhnL[tid] = b_hh[2*H_ + tid];
    // stage h_in: f32 -> hpL, bf16 -> hT[0]
    #pragma unroll
    for (int sweep = 0; sweep < 4; ++sweep) {
        const int u = sweep * 256 + tid, seq = u >> 6, jq = u & 63;
        f32x4 hv = ((const f32x4*)hin)[((size_t)c * BN_ + bn0 + seq) * 64 + jq];
        *(f32x4*)&hpL[seq][jq * 4] = hv;
    }
    #pragma unroll
    for (int sweep = 0; sweep < 2; ++sweep) {
        const int u = sweep * 256 + tid, col = u & 15, kb = (u >> 4) * 8;
        bf16x8 hv = load_pack8(hin + ((size_t)c * BN_ + bn0 + col) * H_ + kb);
        ((bf16x8*)hT)[u] = hv;
    }

    bf16x8 wf[12][8];
    #pragma unroll
    for (int g = 0; g < 3; ++g)
        #pragma unroll
        for (int ms = 0; ms < 4; ++ms) {
            const int row = g * H_ + jb + ms * 16 + lr;
            #pragma unroll
            for (int kt = 0; kt < 8; ++kt)
                wf[g*4 + ms][kt] = *(const bf16x8*)(wbf + (size_t)row * H_ + kt*32 + lg*8);
        }
    __syncthreads();

    const int sb = bn0 >> 4;
    int buf = 0;
    for (int t = 0; t < CL_; ++t) {
        const int tt = c * CL_ + t;
        const int tb = (tt * 32 + sb) * 48;

        u16x4 xv[3][4];
        #pragma unroll
        for (int g = 0; g < 3; ++g)
            #pragma unroll
            for (int ms = 0; ms < 4; ++ms)
                xv[g][ms] = ((const u16x4*)xg2)[(tb + g*16 + wave*4 + ms) * 64 + lane];

        const int d = (m >> t) & 1;
        const short dms = (short)(d ? 0 : -1);

        f32x4 acc[12];
        #pragma unroll
        for (int mt = 0; mt < 8; ++mt) acc[mt] = (f32x4){0.f, 0.f, 0.f, 0.f};
        #pragma unroll
        for (int ms = 0; ms < 4; ++ms)                 // n-gate seeded with b_hh_n
            acc[8 + ms] = *(const f32x4*)&bhnL[jb + ms*16 + lg*4];

        #pragma unroll
        for (int kt = 0; kt < 8; ++kt) {
            bf16x8 hv = *(const bf16x8*)&hT[buf][kt][lg][lr][0];
            hv = hv & dms;
            #pragma unroll
            for (int mt = 0; mt < 12; ++mt)
                acc[mt] = __builtin_amdgcn_mfma_f32_16x16x32_bf16(wf[mt][kt], hv, acc[mt], 0, 0, 0);
        }

        #pragma unroll
        for (int ms = 0; ms < 4; ++ms) {
            const int jq = jb + ms*16 + lg*4;
            f32x4 hp4 = *(const f32x4*)&hpL[lr][jq];
            f32x4 hnew4; u16x4 hb;
            #pragma unroll
            for (int q = 0; q < 4; ++q) {
                float r = sigmoidf_(acc[0 + ms][q] + bf2f(xv[0][ms][q]));
                float z = sigmoidf_(acc[4 + ms][q] + bf2f(xv[1][ms][q]));
                float n = tanhf_(bf2f(xv[2][ms][q]) + r * acc[8 + ms][q]);
                float hpv = d ? 0.0f : hp4[q];
                float hn2 = n + z * (hpv - n);
                hnew4[q] = hn2; hb[q] = f2bf(hn2);
            }
            *(f32x4*)&hpL[lr][jq] = hnew4;
            *(u16x4*)&hT[buf ^ 1][jq >> 5][(jq >> 3) & 3][lr][jq & 7] = hb;
            *(f32x4*)(out + ((size_t)tt * BN_ + bn0 + lr) * H_ + jq) = hnew4;
        }
        __syncthreads();
        buf ^= 1;
    }

    if (c == NC_ - 1) {
        #pragma unroll
        for (int ms = 0; ms < 4; ++ms) {
            const int jq = jb + ms*16 + lg*4;
            f32x4 hv = *(const f32x4*)&hpL[lr][jq];
            *(f32x4*)(out + (size_t)T_ * BN_ * H_ + (size_t)(bn0 + lr) * H_ + jq) = hv;
        }
    }
}

// ---------------------------------------------------------------------------
// Fallback (ws too small): fp32 VALU persistent kernel (correct, slow)
// ---------------------------------------------------------------------------
#define SPB 4
__global__ __launch_bounds__(256, 1)
void slotgru_fallback(const float* __restrict__ x, const int* __restrict__ dones,
                      const float* __restrict__ h0, const float* __restrict__ W_ih,
                      const float* __restrict__ W_hh, const float* __restrict__ b_ih,
                      const float* __restrict__ b_hh, float* __restrict__ out)
{
    __shared__ __align__(16) float xs[SPB][F_];
    __shared__ __align__(16) float hs[SPB][H_];
    const int j = threadIdx.x, bn0 = blockIdx.x * SPB;
    const float bi0 = b_ih[j], bi1 = b_ih[H_ + j], bi2 = b_ih[2*H_ + j];
    const float bh0 = b_hh[j], bh1 = b_hh[H_ + j], bh2 = b_hh[2*H_ + j];
    const float4* wi0 = (const float4*)(W_ih + (size_t)j * F_);
    const float4* wi1 = (const float4*)(W_ih + (size_t)(H_ + j) * F_);
    const float4* wi2 = (const float4*)(W_ih + (size_t)(2*H_ + j) * F_);
    const float4* wh0 = (const float4*)(W_hh + (size_t)j * H_);
    const float4* wh1 = (const float4*)(W_hh + (size_t)(H_ + j) * H_);
    const float4* wh2 = (const float4*)(W_hh + (size_t)(2*H_ + j) * H_);
    float hreg[SPB];
    #pragma unroll
    for (int s = 0; s < SPB; ++s) { float h = h0[(size_t)(bn0+s)*H_ + j]; hreg[s]=h; hs[s][j]=h; }
    for (int t = 0; t < T_; ++t) {
        int d[SPB];
        #pragma unroll
        for (int s = 0; s < SPB; ++s) d[s] = dones[(size_t)t*BN_ + bn0 + s];
        const float* xsrc = x + (size_t)((size_t)t*BN_ + bn0) * F_;
        ((float*)xs)[j] = xsrc[j]; ((float*)xs)[j+256] = xsrc[j+256];
        #pragma unroll
        for (int s = 0; s < SPB; ++s) if (d[s]) hs[s][j] = 0.0f;
        __syncthreads();
        float ax0[SPB]={0,0,0,0}, ax1[SPB]={0,0,0,0}, ax2[SPB]={0,0,0,0};
        #pragma unroll 8
        for (int cc = 0; cc < F_/4; ++cc) {
            float4 w0=wi0[cc], w1=wi1[cc], w2=wi2[cc];
            #pragma unroll
            for (int s = 0; s < SPB; ++s) {
                float4 xv = ((const float4*)xs[s])[cc];
                ax0[s]=fmaf(w0.x,xv.x,fmaf(w0.y,xv.y,fmaf(w0.z,xv.z,fmaf(w0.w,xv.w,ax0[s]))));
                ax1[s]=fmaf(w1.x,xv.x,fmaf(w1.y,xv.y,fmaf(w1.z,xv.z,fmaf(w1.w,xv.w,ax1[s]))));
                ax2[s]=fmaf(w2.x,xv.x,fmaf(w2.y,xv.y,fmaf(w2.z,xv.z,fmaf(w2.w,xv.w,ax2[s]))));
            }
        }
        float ah0[SPB]={0,0,0,0}, ah1[SPB]={0,0,0,0}, ah2[SPB]={0,0,0,0};
        if (!(d[0]&&d[1]&&d[2]&&d[3])) {
            #pragma unroll 4
            for (int cc = 0; cc < H_/4; ++cc) {
                float4 w0=wh0[cc], w1=wh1[cc], w2=wh2[cc];
                #pragma unroll
                for (int s = 0; s < SPB; ++s) if (!d[s]) {
                    float4 hv = ((const float4*)hs[s])[cc];
                    ah0[s]=fmaf(w0.x,hv.x,fmaf(w0.y,hv.y,fmaf(w0.z,hv.z,fmaf(w0.w,hv.w,ah0[s]))));
                    ah1[s]=fmaf(w1.x,hv.x,fmaf(w1.y,hv.y,fmaf(w1.z,hv.z,fmaf(w1.w,hv.w,ah1[s]))));
                    ah2[s]=fmaf(w2.x,hv.x,fmaf(w2.y,hv.y,fmaf(w2.z,hv.z,fmaf(w2.w,hv.w,ah2[s]))));
                }
            }
        }
        float hnew[SPB];
        #pragma unroll
        for (int s = 0; s < SPB; ++s) {
            float hpv = d[s] ? 0.0f : hreg[s];
            float r = sigmoidf_(ax0[s] + bi0 + ah0[s] + bh0);
            float z = sigmoidf_(ax1[s] + bi1 + ah1[s] + bh1);
            float n = tanhf_(ax2[s] + bi2 + r * (ah2[s] + bh2));
            hnew[s] = (1.0f - z) * n + z * hpv;
        }
        __syncthreads();
        #pragma unroll
        for (int s = 0; s < SPB; ++s) {
            hs[s][j] = hnew[s]; hreg[s] = hnew[s];
            out[(size_t)((size_t)t*BN_ + bn0 + s) * H_ + j] = hnew[s];
        }
    }
    #pragma unroll
    for (int s = 0; s < SPB; ++s)
        out[(size_t)T_*BN_*H_ + (size_t)(bn0+s)*H_ + j] = hreg[s];
}

extern "C" void kernel_launch(void* const* d_in, const int* in_sizes, int n_in,
                              void* d_out, int out_size, void* d_ws, size_t ws_size,
                              hipStream_t stream) {
    const float* x     = (const float*)d_in[0];
    const int*   dones = (const int*)  d_in[1];
    const float* h0    = (const float*)d_in[2];
    const float* W_ih  = (const float*)d_in[3];
    const float* W_hh  = (const float*)d_in[4];
    const float* b_ih  = (const float*)d_in[5];
    const float* b_hh  = (const float*)d_in[6];
    float*       out   = (float*)d_out;

    if (ws_size >= WS_NEED) {
        char* ws = (char*)d_ws;
        float*          h1  = (float*)(ws + OFF_H1);
        float*          hin = (float*)(ws + OFF_HIN);
        unsigned short* wbf = (unsigned short*)(ws + OFF_WBF);
        unsigned int*   dmm = (unsigned int*)(ws + OFF_DM);
        unsigned short* xg2 = (unsigned short*)(ws + OFF_XG);

        hipLaunchKernelGGL(xg2_kernel, dim3(2048 + 104), dim3(512), 0, stream,
                           x, W_ih, b_ih, b_hh, W_hh, dones, xg2, wbf, dmm);
        hipLaunchKernelGGL(pass1_kernel, dim3((NC_ - 1) * 32), dim3(256), 0, stream,
                           xg2, dmm, wbf, b_hh, h1);
        hipLaunchKernelGGL(pass2_kernel, dim3(BN_), dim3(256), 0, stream,
                           xg2, dmm, wbf, b_hh, h0, h1, hin);
        hipLaunchKernelGGL(pass3_kernel, dim3(NC_ * 32), dim3(256), 0, stream,
                           xg2, dmm, wbf, b_hh, hin, out);
    } else {
        hipLaunchKernelGGL(slotgru_fallback, dim3(BN_ / SPB), dim3(256), 0, stream,
                           x, dones, h0, W_ih, W_hh, b_ih, b_hh, out);
    }
}

// Round 6
// 354.782 us; speedup vs baseline: 31.4655x; 1.1094x over previous
//
#include <hip/hip_runtime.h>
#include <math.h>

#define T_   256
#define B_   32
#define N_   16
#define F_   128
#define H_   256
#define BN_  512          // B*N
#define G3_  768          // 3*H
#define CL_  32           // chunk length
#define NC_  8            // number of chunks (T_/CL_)

typedef __attribute__((ext_vector_type(8))) short  bf16x8;
typedef __attribute__((ext_vector_type(4))) float  f32x4;
typedef __attribute__((ext_vector_type(4))) unsigned short u16x4;

// ---- workspace layout (bytes) ----
#define OFF_H1   0ULL                                   // f32 [NC][BN][H]   4 MB
#define OFF_HIN  4194304ULL                             // f32 [NC][BN][H]   4 MB
#define OFF_WBF  8388608ULL                             // bf16 [768][256]   384 KB
#define OFF_DM   8781824ULL                             // u32 [NC][BN]      16 KB
#define OFF_XG   8798208ULL                             // bf16 xg2 tiled    192 MB
#define WS_NEED  210124800ULL

__device__ __forceinline__ unsigned short f2bf(float f) {   // RNE float->bf16
    union { float f; unsigned u; } v; v.f = f;
    unsigned u = v.u + 0x7FFFu + ((v.u >> 16) & 1u);
    return (unsigned short)(u >> 16);
}
__device__ __forceinline__ float bf2f(unsigned short h) {
    union { unsigned u; float f; } v; v.u = ((unsigned)h) << 16;
    return v.f;
}
__device__ __forceinline__ bf16x8 load_pack8(const float* __restrict__ p) {
    f32x4 a = *(const f32x4*)p;
    f32x4 b = *(const f32x4*)(p + 4);
    bf16x8 r;
    r[0]=(short)f2bf(a[0]); r[1]=(short)f2bf(a[1]); r[2]=(short)f2bf(a[2]); r[3]=(short)f2bf(a[3]);
    r[4]=(short)f2bf(b[0]); r[5]=(short)f2bf(b[1]); r[6]=(short)f2bf(b[2]); r[7]=(short)f2bf(b[3]);
    return r;
}
__device__ __forceinline__ float sigmoidf_(float x) { return 1.0f / (1.0f + __expf(-x)); }
__device__ __forceinline__ float tanhf_(float x)    { return 1.0f - 2.0f / (__expf(2.0f * x) + 1.0f); }

// Pin a bf16x8 fragment to the AGPR class. The asm body is empty — the
// compiler emits its own v_accvgpr_write copies (hazard rules handled) and
// the MFMA *builtin* can read srcA directly from AGPR (AV operand class),
// so there are no per-use copies and no hand-managed MFMA hazards.
__device__ __forceinline__ bf16x8 pin_a(bf16x8 v) {
    bf16x8 r;
    asm("" : "=a"(r) : "0"(v));
    return r;
}

// xg2 tiled layout: u16 index for element (tt, seq, g)
__device__ __forceinline__ size_t xg2_idx(int tt, int seq, int g) {
    return ((((size_t)tt * 32 + (seq >> 4)) * 48 + (g >> 4)) * 64
            + ((g >> 2) & 3) * 16 + (seq & 15)) * 4 + (g & 3);
}

// ---------------------------------------------------------------------------
// K1: xg2 GEMM (blocks < 1024, 128 seqs per block) + fused prep (>= 1024):
//     wbf = bf16(W_hh); dm = 32-bit done mask per (chunk, seq)
// ---------------------------------------------------------------------------
__global__ __launch_bounds__(512, 2)
void xg2_kernel(const float* __restrict__ x, const float* __restrict__ W_ih,
                const float* __restrict__ b_ih, const float* __restrict__ b_hh,
                const float* __restrict__ W_hh, const int* __restrict__ dones,
                unsigned short* __restrict__ xg2,
                unsigned short* __restrict__ wbf, unsigned int* __restrict__ dm)
{
    const int tid = threadIdx.x;
    if (blockIdx.x >= 1024) {                       // ---- fused prep ----
        const int bid2 = blockIdx.x - 1024;
        if (bid2 < 96) {                            // W_hh f32 -> bf16
            const int i4 = bid2 * 512 + tid;        // 49152 f32x4 units
            f32x4 w = ((const f32x4*)W_hh)[i4];
            u16x4 o;
            #pragma unroll
            for (int q = 0; q < 4; ++q) o[q] = f2bf(w[q]);
            ((u16x4*)wbf)[i4] = o;
        } else {                                    // done masks (u32, CL=32)
            const int u = (bid2 - 96) * 512 + tid;  // 4096 = NC*BN
            const int c = u >> 9, s = u & 511;
            unsigned m = 0;
            #pragma unroll
            for (int k = 0; k < CL_; ++k)
                m |= (dones[(c * CL_ + k) * BN_ + s] ? 1u : 0u) << k;
            dm[c * BN_ + s] = m;
        }
        return;
    }

    __shared__ __align__(16) unsigned short xls[128][136];  // 34816 B, +8 pad
    const int wave = tid >> 6, lane = tid & 63;
    const int lr = lane & 15, lg = lane >> 4;
    const int t   = blockIdx.x >> 2;                // one timestep per block
    const int sb0 = (blockIdx.x & 3) * 8;           // 8 seq-subtiles (128 seqs)
    const int g0  = wave * 96;

    // stage x tile -> bf16 LDS (coalesced f32x4 sweeps)
    #pragma unroll
    for (int sweep = 0; sweep < 8; ++sweep) {
        const int u = sweep * 512 + tid;            // f32x4 unit in [0,4096)
        f32x4 v = ((const f32x4*)x)[(size_t)t * 16384 + sb0 * 512 + u];
        u16x4 o;
        #pragma unroll
        for (int q = 0; q < 4; ++q) o[q] = f2bf(v[q]);
        const int row = u >> 5, col4 = u & 31;
        *(u16x4*)&xls[row][col4 * 4] = o;
    }

    bf16x8 wf[6][4];
    #pragma unroll
    for (int gt = 0; gt < 6; ++gt)
        #pragma unroll
        for (int kt = 0; kt < 4; ++kt)
            wf[gt][kt] = load_pack8(W_ih + (size_t)(g0 + gt*16 + lr) * F_ + kt*32 + lg*8);

    float bv[6][4];
    #pragma unroll
    for (int gt = 0; gt < 6; ++gt)
        #pragma unroll
        for (int q = 0; q < 4; ++q) {
            const int g = g0 + gt*16 + lg*4 + q;
            bv[gt][q] = b_ih[g] + (g < 2*H_ ? b_hh[g] : 0.0f);
        }

    __syncthreads();

    #pragma unroll
    for (int tbt = 0; tbt < 8; ++tbt) {
        bf16x8 xf[4];
        #pragma unroll
        for (int kt = 0; kt < 4; ++kt)
            xf[kt] = *(const bf16x8*)&xls[tbt*16 + lr][kt*32 + lg*8];

        f32x4 acc[6];
        #pragma unroll
        for (int gt = 0; gt < 6; ++gt) acc[gt] = (f32x4){0.f, 0.f, 0.f, 0.f};

        #pragma unroll
        for (int kt = 0; kt < 4; ++kt)
            #pragma unroll
            for (int gt = 0; gt < 6; ++gt)
                acc[gt] = __builtin_amdgcn_mfma_f32_16x16x32_bf16(wf[gt][kt], xf[kt], acc[gt], 0, 0, 0);

        const int sb = sb0 + tbt;
        #pragma unroll
        for (int gt = 0; gt < 6; ++gt) {
            u16x4 o;
            #pragma unroll
            for (int q = 0; q < 4; ++q) o[q] = f2bf(acc[gt][q] + bv[gt][q]);
            const size_t base = (((size_t)t * 32 + sb) * 48 + (wave*6 + gt)) * 64 + lane;
            *(u16x4*)(xg2 + base * 4) = o;
        }
    }
}

// ---------------------------------------------------------------------------
// Recurrent core: 256 threads = 4 waves, 1 wave/SIMD, 1 block/CU.
// Wave w owns j in [64w, 64w+64): 12 m-tiles x 8 k-tiles of W_hh.
// r+z gate weights (64 frags = 256 regs) pinned to AGPRs (pin_a);
// n gate (32 frags = 128 regs) in VGPRs. Loaded ONCE per block.
// All MFMAs are builtins (compiler-managed hazards).
// ---------------------------------------------------------------------------
__global__ __launch_bounds__(256, 1)
void pass1_kernel(const unsigned short* __restrict__ xg2,
                  const unsigned int*  __restrict__ dm,
                  const unsigned short* __restrict__ wbf,
                  const float* __restrict__ b_hh,
                  float* __restrict__ h1)
{
    __shared__ __align__(16) unsigned short hT[2][8][4][16][8];   // 16 KB
    __shared__ __align__(16) float hpL[16][260];                  // 16.6 KB
    __shared__ float bhnL[H_];                                    // 1 KB

    const int tid  = threadIdx.x;
    const int wave = tid >> 6, lane = tid & 63;
    const int lr = lane & 15, lg = lane >> 4;
    const int c   = blockIdx.x >> 5;            // 0..NC_-2
    const int bn0 = (blockIdx.x & 31) * 16;
    const int jb  = wave * 64;

    const unsigned m = dm[c * BN_ + bn0 + lr];
    if (__ballot(m != 0) == 0ULL) return;       // whole group transparent

    int last = m ? (31 - __builtin_clz(m)) : 31;
    #pragma unroll
    for (int w = 1; w < 16; w <<= 1) last = min(last, __shfl_xor(last, w));

    bhnL[tid] = b_hh[2*H_ + tid];
    #pragma unroll
    for (int sweep = 0; sweep < 2; ++sweep)
        ((bf16x8*)hT)[sweep * 256 + tid] = (bf16x8)(short)0;
    #pragma unroll
    for (int sweep = 0; sweep < 4; ++sweep) {
        const int u = sweep * 256 + tid, seq = u >> 6, jq = u & 63;
        *(f32x4*)&hpL[seq][jq * 4] = (f32x4){0.f, 0.f, 0.f, 0.f};
    }

    // r+z gate weights -> AGPR (pinned); n gate -> VGPR
    bf16x8 wfa[8][8];   // mt = g*4+ms, g in {0(r),1(z)}
    bf16x8 wfv[4][8];   // n gate, ms 0..3
    #pragma unroll
    for (int mt = 0; mt < 8; ++mt) {
        const int row = (mt >> 2) * H_ + jb + (mt & 3) * 16 + lr;
        #pragma unroll
        for (int kt = 0; kt < 8; ++kt)
            wfa[mt][kt] = pin_a(*(const bf16x8*)(wbf + (size_t)row * H_ + kt*32 + lg*8));
    }
    #pragma unroll
    for (int ms = 0; ms < 4; ++ms) {
        const int row = 2 * H_ + jb + ms * 16 + lr;
        #pragma unroll
        for (int kt = 0; kt < 8; ++kt)
            wfv[ms][kt] = *(const bf16x8*)(wbf + (size_t)row * H_ + kt*32 + lg*8);
    }
    __syncthreads();

    const int sb = bn0 >> 4;
    int buf = 0;
    for (int t = last; t < CL_; ++t) {
        const int tt = c * CL_ + t;
        const int tb = (tt * 32 + sb) * 48;

        u16x4 xv[3][4];
        #pragma unroll
        for (int g = 0; g < 3; ++g)
            #pragma unroll
            for (int ms = 0; ms < 4; ++ms)
                xv[g][ms] = ((const u16x4*)xg2)[(size_t)(tb + g*16 + wave*4 + ms) * 64 + lane];

        const int d = (m >> t) & 1;
        const short dms = (short)(d ? 0 : -1);

        f32x4 acc[12];
        #pragma unroll
        for (int mt = 0; mt < 8; ++mt) acc[mt] = (f32x4){0.f, 0.f, 0.f, 0.f};
        #pragma unroll
        for (int ms = 0; ms < 4; ++ms)                 // n-gate seeded with b_hh_n
            acc[8 + ms] = *(const f32x4*)&bhnL[jb + ms*16 + lg*4];

        #pragma unroll
        for (int kt = 0; kt < 8; ++kt) {
            bf16x8 hv = *(const bf16x8*)&hT[buf][kt][lg][lr][0];
            hv = hv & dms;
            #pragma unroll
            for (int mt = 0; mt < 8; ++mt)
                acc[mt] = __builtin_amdgcn_mfma_f32_16x16x32_bf16(wfa[mt][kt], hv, acc[mt], 0, 0, 0);
            #pragma unroll
            for (int ms = 0; ms < 4; ++ms)
                acc[8 + ms] = __builtin_amdgcn_mfma_f32_16x16x32_bf16(wfv[ms][kt], hv, acc[8 + ms], 0, 0, 0);
        }

        #pragma unroll
        for (int ms = 0; ms < 4; ++ms) {
            const int jq = jb + ms*16 + lg*4;
            f32x4 hp4 = *(const f32x4*)&hpL[lr][jq];
            f32x4 hnew4; u16x4 hb;
            #pragma unroll
            for (int q = 0; q < 4; ++q) {
                float r = sigmoidf_(acc[0 + ms][q] + bf2f(xv[0][ms][q]));
                float z = sigmoidf_(acc[4 + ms][q] + bf2f(xv[1][ms][q]));
                float n = tanhf_(bf2f(xv[2][ms][q]) + r * acc[8 + ms][q]);
                float hpv = d ? 0.0f : hp4[q];
                float hn2 = n + z * (hpv - n);
                hnew4[q] = hn2; hb[q] = f2bf(hn2);
            }
            *(f32x4*)&hpL[lr][jq] = hnew4;
            *(u16x4*)&hT[buf ^ 1][jq >> 5][(jq >> 3) & 3][lr][jq & 7] = hb;
        }
        __syncthreads();
        buf ^= 1;
    }

    #pragma unroll
    for (int ms = 0; ms < 4; ++ms) {
        const int jq = jb + ms*16 + lg*4;
        f32x4 hv = *(const f32x4*)&hpL[lr][jq];
        *(f32x4*)(h1 + ((size_t)c * BN_ + bn0 + lr) * H_ + jq) = hv;
    }
}

// ---------------------------------------------------------------------------
// pass2: chain h across chunks. Copy when chunk has a done; rare VALU GRU.
// ---------------------------------------------------------------------------
__global__ __launch_bounds__(256)
void pass2_kernel(const unsigned short* __restrict__ xg2,
                  const unsigned int*  __restrict__ dm,
                  const unsigned short* __restrict__ wbf,
                  const float* __restrict__ b_hh,
                  const float* __restrict__ h0,
                  const float* __restrict__ h1,
                  float* __restrict__ hin)
{
    __shared__ unsigned short hsb[H_];
    const int s = blockIdx.x, j = threadIdx.x;
    float h = h0[(size_t)s * H_ + j];
    const float bhn = b_hh[2*H_ + j];

    for (int c = 0; c < NC_; ++c) {
        hin[((size_t)c * BN_ + s) * H_ + j] = h;
        if (c == NC_ - 1) break;
        const unsigned m = dm[c * BN_ + s];         // block-uniform
        if (m) {
            h = h1[((size_t)c * BN_ + s) * H_ + j];
        } else {
            for (int t = 0; t < CL_; ++t) {
                hsb[j] = f2bf(h);
                __syncthreads();
                float a0 = 0.f, a1 = 0.f, a2 = 0.f;
                for (int k = 0; k < H_; ++k) {
                    float hk = bf2f(hsb[k]);
                    a0 = fmaf(bf2f(wbf[(size_t)j * H_ + k]),          hk, a0);
                    a1 = fmaf(bf2f(wbf[(size_t)(H_ + j) * H_ + k]),   hk, a1);
                    a2 = fmaf(bf2f(wbf[(size_t)(2*H_ + j) * H_ + k]), hk, a2);
                }
                const int tt = c * CL_ + t;
                float xr = bf2f(xg2[xg2_idx(tt, s, j)]);
                float xz = bf2f(xg2[xg2_idx(tt, s, H_ + j)]);
                float xn = bf2f(xg2[xg2_idx(tt, s, 2*H_ + j)]);
                float r = sigmoidf_(a0 + xr);
                float z = sigmoidf_(a1 + xz);
                float n = tanhf_(xn + r * (a2 + bhn));
                h = n + z * (h - n);
                __syncthreads();
            }
        }
    }
}

// ---------------------------------------------------------------------------
// pass3: from known h_in, compute all outputs. Same core as pass1 + out stores.
// ---------------------------------------------------------------------------
__global__ __launch_bounds__(256, 1)
void pass3_kernel(const unsigned short* __restrict__ xg2,
                  const unsigned int*  __restrict__ dm,
                  const unsigned short* __restrict__ wbf,
                  const float* __restrict__ b_hh,
                  const float* __restrict__ hin,
                  float* __restrict__ out)
{
    __shared__ __align__(16) unsigned short hT[2][8][4][16][8];   // 16 KB
    __shared__ __align__(16) float hpL[16][260];                  // 16.6 KB
    __shared__ float bhnL[H_];                                    // 1 KB

    const int tid  = threadIdx.x;
    const int wave = tid >> 6, lane = tid & 63;
    const int lr = lane & 15, lg = lane >> 4;
    const int c   = blockIdx.x >> 5;            // 0..NC_-1
    const int bn0 = (blockIdx.x & 31) * 16;
    const int jb  = wave * 64;

    const unsigned m = dm[c * BN_ + bn0 + lr];

    bhnL[tid] = b_hh[2*H_ + tid];
    // stage h_in: f32 -> hpL, bf16 -> hT[0]
    #pragma unroll
    for (int sweep = 0; sweep < 4; ++sweep) {
        const int u = sweep * 256 + tid, seq = u >> 6, jq = u & 63;
        f32x4 hv = ((const f32x4*)hin)[((size_t)c * BN_ + bn0 + seq) * 64 + jq];
        *(f32x4*)&hpL[seq][jq * 4] = hv;
    }
    #pragma unroll
    for (int sweep = 0; sweep < 2; ++sweep) {
        const int u = sweep * 256 + tid, col = u & 15, kb = (u >> 4) * 8;
        bf16x8 hv = load_pack8(hin + ((size_t)c * BN_ + bn0 + col) * H_ + kb);
        ((bf16x8*)hT)[u] = hv;
    }

    bf16x8 wfa[8][8];
    bf16x8 wfv[4][8];
    #pragma unroll
    for (int mt = 0; mt < 8; ++mt) {
        const int row = (mt >> 2) * H_ + jb + (mt & 3) * 16 + lr;
        #pragma unroll
        for (int kt = 0; kt < 8; ++kt)
            wfa[mt][kt] = pin_a(*(const bf16x8*)(wbf + (size_t)row * H_ + kt*32 + lg*8));
    }
    #pragma unroll
    for (int ms = 0; ms < 4; ++ms) {
        const int row = 2 * H_ + jb + ms * 16 + lr;
        #pragma unroll
        for (int kt = 0; kt < 8; ++kt)
            wfv[ms][kt] = *(const bf16x8*)(wbf + (size_t)row * H_ + kt*32 + lg*8);
    }
    __syncthreads();

    const int sb = bn0 >> 4;
    int buf = 0;
    for (int t = 0; t < CL_; ++t) {
        const int tt = c * CL_ + t;
        const int tb = (tt * 32 + sb) * 48;

        u16x4 xv[3][4];
        #pragma unroll
        for (int g = 0; g < 3; ++g)
            #pragma unroll
            for (int ms = 0; ms < 4; ++ms)
                xv[g][ms] = ((const u16x4*)xg2)[(size_t)(tb + g*16 + wave*4 + ms) * 64 + lane];

        const int d = (m >> t) & 1;
        const short dms = (short)(d ? 0 : -1);

        f32x4 acc[12];
        #pragma unroll
        for (int mt = 0; mt < 8; ++mt) acc[mt] = (f32x4){0.f, 0.f, 0.f, 0.f};
        #pragma unroll
        for (int ms = 0; ms < 4; ++ms)                 // n-gate seeded with b_hh_n
            acc[8 + ms] = *(const f32x4*)&bhnL[jb + ms*16 + lg*4];

        #pragma unroll
        for (int kt = 0; kt < 8; ++kt) {
            bf16x8 hv = *(const bf16x8*)&hT[buf][kt][lg][lr][0];
            hv = hv & dms;
            #pragma unroll
            for (int mt = 0; mt < 8; ++mt)
                acc[mt] = __builtin_amdgcn_mfma_f32_16x16x32_bf16(wfa[mt][kt], hv, acc[mt], 0, 0, 0);
            #pragma unroll
            for (int ms = 0; ms < 4; ++ms)
                acc[8 + ms] = __builtin_amdgcn_mfma_f32_16x16x32_bf16(wfv[ms][kt], hv, acc[8 + ms], 0, 0, 0);
        }

        #pragma unroll
        for (int ms = 0; ms < 4; ++ms) {
            const int jq = jb + ms*16 + lg*4;
            f32x4 hp4 = *(const f32x4*)&hpL[lr][jq];
            f32x4 hnew4; u16x4 hb;
            #pragma unroll
            for (int q = 0; q < 4; ++q) {
                float r = sigmoidf_(acc[0 + ms][q] + bf2f(xv[0][ms][q]));
                float z = sigmoidf_(acc[4 + ms][q] + bf2f(xv[1][ms][q]));
                float n = tanhf_(bf2f(xv[2][ms][q]) + r * acc[8 + ms][q]);
                float hpv = d ? 0.0f : hp4[q];
                float hn2 = n + z * (hpv - n);
                hnew4[q] = hn2; hb[q] = f2bf(hn2);
            }
            *(f32x4*)&hpL[lr][jq] = hnew4;
            *(u16x4*)&hT[buf ^ 1][jq >> 5][(jq >> 3) & 3][lr][jq & 7] = hb;
            *(f32x4*)(out + ((size_t)tt * BN_ + bn0 + lr) * H_ + jq) = hnew4;
        }
        __syncthreads();
        buf ^= 1;
    }

    if (c == NC_ - 1) {
        #pragma unroll
        for (int ms = 0; ms < 4; ++ms) {
            const int jq = jb + ms*16 + lg*4;
            f32x4 hv = *(const f32x4*)&hpL[lr][jq];
            *(f32x4*)(out + (size_t)T_ * BN_ * H_ + (size_t)(bn0 + lr) * H_ + jq) = hv;
        }
    }
}

// ---------------------------------------------------------------------------
// Fallback (ws too small): fp32 VALU persistent kernel (correct, slow)
// ---------------------------------------------------------------------------
#define SPB 4
__global__ __launch_bounds__(256, 1)
void slotgru_fallback(const float* __restrict__ x, const int* __restrict__ dones,
                      const float* __restrict__ h0, const float* __restrict__ W_ih,
                      const float* __restrict__ W_hh, const float* __restrict__ b_ih,
                      const float* __restrict__ b_hh, float* __restrict__ out)
{
    __shared__ __align__(16) float xs[SPB][F_];
    __shared__ __align__(16) float hs[SPB][H_];
    const int j = threadIdx.x, bn0 = blockIdx.x * SPB;
    const float bi0 = b_ih[j], bi1 = b_ih[H_ + j], bi2 = b_ih[2*H_ + j];
    const float bh0 = b_hh[j], bh1 = b_hh[H_ + j], bh2 = b_hh[2*H_ + j];
    const float4* wi0 = (const float4*)(W_ih + (size_t)j * F_);
    const float4* wi1 = (const float4*)(W_ih + (size_t)(H_ + j) * F_);
    const float4* wi2 = (const float4*)(W_ih + (size_t)(2*H_ + j) * F_);
    const float4* wh0 = (const float4*)(W_hh + (size_t)j * H_);
    const float4* wh1 = (const float4*)(W_hh + (size_t)(H_ + j) * H_);
    const float4* wh2 = (const float4*)(W_hh + (size_t)(2*H_ + j) * H_);
    float hreg[SPB];
    #pragma unroll
    for (int s = 0; s < SPB; ++s) { float h = h0[(size_t)(bn0+s)*H_ + j]; hreg[s]=h; hs[s][j]=h; }
    for (int t = 0; t < T_; ++t) {
        int d[SPB];
        #pragma unroll
        for (int s = 0; s < SPB; ++s) d[s] = dones[(size_t)t*BN_ + bn0 + s];
        const float* xsrc = x + (size_t)((size_t)t*BN_ + bn0) * F_;
        ((float*)xs)[j] = xsrc[j]; ((float*)xs)[j+256] = xsrc[j+256];
        #pragma unroll
        for (int s = 0; s < SPB; ++s) if (d[s]) hs[s][j] = 0.0f;
        __syncthreads();
        float ax0[SPB]={0,0,0,0}, ax1[SPB]={0,0,0,0}, ax2[SPB]={0,0,0,0};
        #pragma unroll 8
        for (int cc = 0; cc < F_/4; ++cc) {
            float4 w0=wi0[cc], w1=wi1[cc], w2=wi2[cc];
            #pragma unroll
            for (int s = 0; s < SPB; ++s) {
                float4 xv = ((const float4*)xs[s])[cc];
                ax0[s]=fmaf(w0.x,xv.x,fmaf(w0.y,xv.y,fmaf(w0.z,xv.z,fmaf(w0.w,xv.w,ax0[s]))));
                ax1[s]=fmaf(w1.x,xv.x,fmaf(w1.y,xv.y,fmaf(w1.z,xv.z,fmaf(w1.w,xv.w,ax1[s]))));
                ax2[s]=fmaf(w2.x,xv.x,fmaf(w2.y,xv.y,fmaf(w2.z,xv.z,fmaf(w2.w,xv.w,ax2[s]))));
            }
        }
        float ah0[SPB]={0,0,0,0}, ah1[SPB]={0,0,0,0}, ah2[SPB]={0,0,0,0};
        if (!(d[0]&&d[1]&&d[2]&&d[3])) {
            #pragma unroll 4
            for (int cc = 0; cc < H_/4; ++cc) {
                float4 w0=wh0[cc], w1=wh1[cc], w2=wh2[cc];
                #pragma unroll
                for (int s = 0; s < SPB; ++s) if (!d[s]) {
                    float4 hv = ((const float4*)hs[s])[cc];
                    ah0[s]=fmaf(w0.x,hv.x,fmaf(w0.y,hv.y,fmaf(w0.z,hv.z,fmaf(w0.w,hv.w,ah0[s]))));
                    ah1[s]=fmaf(w1.x,hv.x,fmaf(w1.y,hv.y,fmaf(w1.z,hv.z,fmaf(w1.w,hv.w,ah1[s]))));
                    ah2[s]=fmaf(w2.x,hv.x,fmaf(w2.y,hv.y,fmaf(w2.z,hv.z,fmaf(w2.w,hv.w,ah2[s]))));
                }
            }
        }
        float hnew[SPB];
        #pragma unroll
        for (int s = 0; s < SPB; ++s) {
            float hpv = d[s] ? 0.0f : hreg[s];
            float r = sigmoidf_(ax0[s] + bi0 + ah0[s] + bh0);
            float z = sigmoidf_(ax1[s] + bi1 + ah1[s] + bh1);
            float n = tanhf_(ax2[s] + bi2 + r * (ah2[s] + bh2));
            hnew[s] = (1.0f - z) * n + z * hpv;
        }
        __syncthreads();
        #pragma unroll
        for (int s = 0; s < SPB; ++s) {
            hs[s][j] = hnew[s]; hreg[s] = hnew[s];
            out[(size_t)((size_t)t*BN_ + bn0 + s) * H_ + j] = hnew[s];
        }
    }
    #pragma unroll
    for (int s = 0; s < SPB; ++s)
        out[(size_t)T_*BN_*H_ + (size_t)(bn0+s)*H_ + j] = hreg[s];
}

extern "C" void kernel_launch(void* const* d_in, const int* in_sizes, int n_in,
                              void* d_out, int out_size, void* d_ws, size_t ws_size,
                              hipStream_t stream) {
    const float* x     = (const float*)d_in[0];
    const int*   dones = (const int*)  d_in[1];
    const float* h0    = (const float*)d_in[2];
    const float* W_ih  = (const float*)d_in[3];
    const float* W_hh  = (const float*)d_in[4];
    const float* b_ih  = (const float*)d_in[5];
    const float* b_hh  = (const float*)d_in[6];
    float*       out   = (float*)d_out;

    if (ws_size >= WS_NEED) {
        char* ws = (char*)d_ws;
        float*          h1  = (float*)(ws + OFF_H1);
        float*          hin = (float*)(ws + OFF_HIN);
        unsigned short* wbf = (unsigned short*)(ws + OFF_WBF);
        unsigned int*   dmm = (unsigned int*)(ws + OFF_DM);
        unsigned short* xg2 = (unsigned short*)(ws + OFF_XG);

        hipLaunchKernelGGL(xg2_kernel, dim3(1024 + 104), dim3(512), 0, stream,
                           x, W_ih, b_ih, b_hh, W_hh, dones, xg2, wbf, dmm);
        hipLaunchKernelGGL(pass1_kernel, dim3((NC_ - 1) * 32), dim3(256), 0, stream,
                           xg2, dmm, wbf, b_hh, h1);
        hipLaunchKernelGGL(pass2_kernel, dim3(BN_), dim3(256), 0, stream,
                           xg2, dmm, wbf, b_hh, h0, h1, hin);
        hipLaunchKernelGGL(pass3_kernel, dim3(NC_ * 32), dim3(256), 0, stream,
                           xg2, dmm, wbf, b_hh, hin, out);
    } else {
        hipLaunchKernelGGL(slotgru_fallback, dim3(BN_ / SPB), dim3(256), 0, stream,
                           x, dones, h0, W_ih, W_hh, b_ih, b_hh, out);
    }
}